// Round 11
// baseline (315.650 us; speedup 1.0000x reference)
//
#include <hip/hip_runtime.h>

#define N_NODES 20000
#define N_EDGES 320000
#define ET (N_EDGES + N_NODES)   // 340000 edges incl self-loops
#define F_IN 1024
#define HC 256                   // H*C for layers 1,2
#define NC 4

typedef unsigned short ushort_t;
typedef __attribute__((ext_vector_type(8))) short short8;
typedef __attribute__((ext_vector_type(4))) float f32x4;

// bf16 <-> f32 via bit ops (RTNE)
__device__ inline ushort_t f2bf(float f) {
    unsigned u = __float_as_uint(f);
    unsigned r = (u + 0x7fffu + ((u >> 16) & 1u)) >> 16;
    return (ushort_t)r;
}
__device__ inline float bf2f(ushort_t u) {
    return __uint_as_float(((unsigned)u) << 16);
}

// packed f32x2 -> bf16x2 (lo in bits 15:0, hi in bits 31:16), HW RTNE
__device__ inline unsigned cvt_pk_bf16(float lo, float hi) {
    unsigned r;
    asm("v_cvt_pk_bf16_f32 %0, %1, %2" : "=v"(r) : "v"(lo), "v"(hi));
    return r;
}

#define GLOAD16(gp, lp) __builtin_amdgcn_global_load_lds( \
    (const __attribute__((address_space(1))) void*)(gp),  \
    (__attribute__((address_space(3))) void*)(lp), 16, 0, 0)

// ---------------- CSR build ----------------
__global__ void count_kernel(const int* __restrict__ ei, int* __restrict__ counts) {
    int e = blockIdx.x * blockDim.x + threadIdx.x;
    if (e >= ET) return;
    int dst = (e < N_EDGES) ? ei[N_EDGES + e] : (e - N_EDGES);
    atomicAdd(&counts[dst], 1);
}

__global__ void scan_kernel(const int* __restrict__ counts, int* __restrict__ row_ptr,
                            int* __restrict__ cursor) {
    __shared__ int sums[1024];
    int t = threadIdx.x;
    const int per = (N_NODES + 1023) / 1024;
    int b = t * per;
    int e = min(b + per, N_NODES);
    int s = 0;
    for (int i = b; i < e; ++i) s += counts[i];
    sums[t] = s;
    __syncthreads();
    for (int off = 1; off < 1024; off <<= 1) {
        int v = (t >= off) ? sums[t - off] : 0;
        __syncthreads();
        sums[t] += v;
        __syncthreads();
    }
    int run = (t == 0) ? 0 : sums[t - 1];
    for (int i = b; i < e; ++i) {
        row_ptr[i] = run;
        cursor[i]  = run;
        run += counts[i];
    }
    if (t == 0) row_ptr[N_NODES] = ET;
}

__global__ void scatter_kernel(const int* __restrict__ ei, int* __restrict__ cursor,
                               int* __restrict__ col) {
    int e = blockIdx.x * blockDim.x + threadIdx.x;
    if (e >= ET) return;
    int src, dst;
    if (e < N_EDGES) { src = ei[e]; dst = ei[N_EDGES + e]; }
    else             { src = dst = e - N_EDGES; }
    int pos = atomicAdd(&cursor[dst], 1);
    col[pos] = src;
}

// weights: in [K][Nn] fp32 row-major -> hi/lo W^T [Nn][K] bf16
__global__ void split_T(const float* __restrict__ in, ushort_t* __restrict__ hi,
                        ushort_t* __restrict__ lo, int K, int Nn) {
    int idx = blockIdx.x * blockDim.x + threadIdx.x;
    if (idx >= K * Nn) return;
    int k = idx / Nn, n = idx - k * Nn;
    float v = in[idx];
    ushort_t h = f2bf(v);
    hi[(size_t)n * K + k] = h;
    lo[(size_t)n * K + k] = f2bf(v - bf2f(h));
}

// ---------------- GEMM1: fp32 A, cvt_pk split, 2-phase double-buffered ----------------
template<int GY>
__launch_bounds__(256)
__global__ void gemm_f32a(const float* __restrict__ X,
                          const ushort_t* __restrict__ BTh, const ushort_t* __restrict__ BTl,
                          float* __restrict__ C, int M, int K, int NT) {
    constexpr int BM = 64, BN = 64, SM = 32, SN = 32, MF = 2, NF = 2;
    constexpr int BUFB = 4 * 64 * 64;          // 16 KB per buffer
    __shared__ __align__(16) char smem[2 * BUFB];

    const int t = threadIdx.x, lane = t & 63, w = t >> 6;
    const int wm = w >> 1, wn = w & 1;
    const int nwg = gridDim.x;
    const int id = blockIdx.x;
    const int q = nwg >> 3, r = nwg & 7;
    const int xcd = id & 7, idx = id >> 3;
    const int logical = (xcd < r ? xcd * (q + 1) : r * (q + 1) + (xcd - r) * q) + idx;
    const int bm = (logical / GY) * BM, bn = (logical % GY) * BN;

    // A staging geometry
    const int arow = w * 16 + (lane >> 2);
    const int achk = lane & 3;
    const int grow = min(bm + arow, M - 1);
    const float* xRow = X + (size_t)grow * K + achk * 8;
    const int aoff = arow * 64 + ((achk ^ ((arow >> 1) & 3)) * 16);

    // B staging (gload_lds, pre-swizzled source)
    const int gchunk = ((lane & 3) ^ ((lane >> 3) & 3)) * 16;
    const int brow = w * 16 + (lane >> 2);
    const size_t gB = (size_t)(bn + brow) * K * 2 + gchunk;
    const int lB = w * 1024;

    const char* Bhb = (const char*)BTh;
    const char* Blb = (const char*)BTl;
    const int c16 = (lane >> 4);
    const int NTs = K / 32;

    f32x4 acc[MF][NF];
    #pragma unroll
    for (int i = 0; i < MF; ++i)
        #pragma unroll
        for (int j = 0; j < NF; ++j) acc[i][j] = (f32x4){0.f, 0.f, 0.f, 0.f};

    auto conv_write = [&](char* base, float4 v0, float4 v1) {
        float vv[8] = {v0.x, v0.y, v0.z, v0.w, v1.x, v1.y, v1.z, v1.w};
        unsigned hp[4], lp[4];
        #pragma unroll
        for (int j = 0; j < 4; ++j) {
            unsigned h = cvt_pk_bf16(vv[2 * j], vv[2 * j + 1]);
            float h0 = __uint_as_float(h << 16);
            float h1 = __uint_as_float(h & 0xFFFF0000u);
            hp[j] = h;
            lp[j] = cvt_pk_bf16(vv[2 * j] - h0, vv[2 * j + 1] - h1);
        }
        *(uint4*)(base + aoff)        = make_uint4(hp[0], hp[1], hp[2], hp[3]);  // A-hi
        *(uint4*)(base + 4096 + aoff) = make_uint4(lp[0], lp[1], lp[2], lp[3]);  // A-lo
    };

    // ---- prologue: stage tile 0, prefetch A regs for tile 1 ----
    float4 a0 = *(const float4*)(xRow);
    float4 a1 = *(const float4*)(xRow + 4);
    conv_write(smem, a0, a1);
    GLOAD16(Bhb + gB, smem + 8192 + lB);
    GLOAD16(Blb + gB, smem + 12288 + lB);
    float4 b0, b1;
    if (NTs > 1) {
        b0 = *(const float4*)(xRow + 32);
        b1 = *(const float4*)(xRow + 36);
    }
    __syncthreads();

    for (int ts = 0; ts < NTs; ++ts) {
        char* cur = smem + (ts & 1) * BUFB;
        char* nxt = smem + ((ts & 1) ^ 1) * BUFB;
        // prefetch A regs for ts+2 (full iteration of slack)
        float4 c0, c1;
        if (ts + 2 < NTs) {
            c0 = *(const float4*)(xRow + (ts + 2) * 32);
            c1 = *(const float4*)(xRow + (ts + 2) * 32 + 4);
        }
        // stage tile ts+1 (flies during this tile's compute)
        if (ts + 1 < NTs) {
            conv_write(nxt, b0, b1);
            size_t kb = (size_t)(ts + 1) * 64;
            GLOAD16(Bhb + gB + kb, nxt + 8192 + lB);
            GLOAD16(Blb + gB + kb, nxt + 12288 + lB);
        }
        // compute tile ts
        short8 afh[MF], afl[MF], bfh[NF], bfl[NF];
        #pragma unroll
        for (int i = 0; i < MF; ++i) {
            int row = wm * SM + i * 16 + (lane & 15);
            int off = row * 64 + ((c16 ^ ((row >> 1) & 3)) * 16);
            afh[i] = *(const short8*)(cur + off);
            afl[i] = *(const short8*)(cur + 4096 + off);
        }
        #pragma unroll
        for (int j = 0; j < NF; ++j) {
            int row = wn * SN + j * 16 + (lane & 15);
            int off = row * 64 + ((c16 ^ ((row >> 1) & 3)) * 16);
            bfh[j] = *(const short8*)(cur + 8192 + off);
            bfl[j] = *(const short8*)(cur + 12288 + off);
        }
        #pragma unroll
        for (int i = 0; i < MF; ++i)
            #pragma unroll
            for (int j = 0; j < NF; ++j) {
                acc[i][j] = __builtin_amdgcn_mfma_f32_16x16x32_bf16(afh[i], bfh[j], acc[i][j], 0, 0, 0);
                acc[i][j] = __builtin_amdgcn_mfma_f32_16x16x32_bf16(afh[i], bfl[j], acc[i][j], 0, 0, 0);
                acc[i][j] = __builtin_amdgcn_mfma_f32_16x16x32_bf16(afl[i], bfh[j], acc[i][j], 0, 0, 0);
            }
        __syncthreads();    // drains lgkm (A ds_write) + vmcnt (B gloads) for tile ts+1
        b0 = c0; b1 = c1;
    }
    #pragma unroll
    for (int i = 0; i < MF; ++i) {
        int rbase = bm + wm * SM + i * 16 + (lane >> 4) * 4;
        #pragma unroll
        for (int j = 0; j < NF; ++j) {
            int col = bn + wn * SN + j * 16 + (lane & 15);
            #pragma unroll
            for (int rr = 0; rr < 4; ++rr)
                if (rbase + rr < M) C[(size_t)(rbase + rr) * NT + col] = acc[i][j][rr];
        }
    }
}

// ---------------- split-bf16 MFMA GEMM (bf16 A), 2-phase double-buffered ----------------
template<int GY>
__launch_bounds__(256)
__global__ void gemm_mfma(const ushort_t* __restrict__ Ah, const ushort_t* __restrict__ Al,
                          const ushort_t* __restrict__ BTh, const ushort_t* __restrict__ BTl,
                          float* __restrict__ C, int M, int K, int NT) {
    constexpr int BM = 64, BN = 64, SM = 32, SN = 32, MF = 2, NF = 2;
    constexpr int BUFB = 4 * 64 * 64;          // 16 KB per buffer
    __shared__ __align__(16) char smem[2 * BUFB];

    const int t = threadIdx.x, lane = t & 63, w = t >> 6;
    const int wm = w >> 1, wn = w & 1;
    const int nwg = gridDim.x;
    const int id = blockIdx.x;
    const int q = nwg >> 3, r = nwg & 7;
    const int xcd = id & 7, idx = id >> 3;
    const int logical = (xcd < r ? xcd * (q + 1) : r * (q + 1) + (xcd - r) * q) + idx;
    const int bm = (logical / GY) * BM, bn = (logical % GY) * BN;
    const int gchunk = ((lane & 3) ^ ((lane >> 3) & 3)) * 16;  // pre-swizzled source

    const int srow = w * 16 + (lane >> 2);
    const int grow = min(bm + srow, M - 1);
    const size_t gA = (size_t)grow * K * 2 + gchunk;
    const size_t gB = (size_t)(bn + srow) * K * 2 + gchunk;
    const int lS = w * 1024;

    const char* Ahb = (const char*)Ah;
    const char* Alb = (const char*)Al;
    const char* Bhb = (const char*)BTh;
    const char* Blb = (const char*)BTl;
    const int c16 = (lane >> 4);
    const int NTs = K / 32;

    f32x4 acc[MF][NF];
    #pragma unroll
    for (int i = 0; i < MF; ++i)
        #pragma unroll
        for (int j = 0; j < NF; ++j) acc[i][j] = (f32x4){0.f, 0.f, 0.f, 0.f};

    auto stage = [&](char* base, int ts) {
        size_t kb = (size_t)ts * 64;
        GLOAD16(Ahb + gA + kb, base + lS);
        GLOAD16(Alb + gA + kb, base + 4096 + lS);
        GLOAD16(Bhb + gB + kb, base + 8192 + lS);
        GLOAD16(Blb + gB + kb, base + 12288 + lS);
    };

    stage(smem, 0);
    __syncthreads();

    for (int ts = 0; ts < NTs; ++ts) {
        char* cur = smem + (ts & 1) * BUFB;
        char* nxt = smem + ((ts & 1) ^ 1) * BUFB;
        if (ts + 1 < NTs) stage(nxt, ts + 1);
        short8 afh[MF], afl[MF], bfh[NF], bfl[NF];
        #pragma unroll
        for (int i = 0; i < MF; ++i) {
            int row = wm * SM + i * 16 + (lane & 15);
            int off = row * 64 + ((c16 ^ ((row >> 1) & 3)) * 16);
            afh[i] = *(const short8*)(cur + off);
            afl[i] = *(const short8*)(cur + 4096 + off);
        }
        #pragma unroll
        for (int j = 0; j < NF; ++j) {
            int row = wn * SN + j * 16 + (lane & 15);
            int off = row * 64 + ((c16 ^ ((row >> 1) & 3)) * 16);
            bfh[j] = *(const short8*)(cur + 8192 + off);
            bfl[j] = *(const short8*)(cur + 12288 + off);
        }
        #pragma unroll
        for (int i = 0; i < MF; ++i)
            #pragma unroll
            for (int j = 0; j < NF; ++j) {
                acc[i][j] = __builtin_amdgcn_mfma_f32_16x16x32_bf16(afh[i], bfh[j], acc[i][j], 0, 0, 0);
                acc[i][j] = __builtin_amdgcn_mfma_f32_16x16x32_bf16(afh[i], bfl[j], acc[i][j], 0, 0, 0);
                acc[i][j] = __builtin_amdgcn_mfma_f32_16x16x32_bf16(afl[i], bfh[j], acc[i][j], 0, 0, 0);
            }
        __syncthreads();
    }
    #pragma unroll
    for (int i = 0; i < MF; ++i) {
        int rbase = bm + wm * SM + i * 16 + (lane >> 4) * 4;
        #pragma unroll
        for (int j = 0; j < NF; ++j) {
            int col = bn + wn * SN + j * 16 + (lane & 15);
            #pragma unroll
            for (int rr = 0; rr < 4; ++rr)
                if (rbase + rr < M) C[(size_t)(rbase + rr) * NT + col] = acc[i][j][rr];
        }
    }
}

// ---------------- attention logits ----------------
template<int H>
__global__ void al_kernel(const float* __restrict__ h, const float* __restrict__ as_w,
                          const float* __restrict__ ad_w, float* __restrict__ als,
                          float* __restrict__ ald) {
    int n = blockIdx.x;
    int t = threadIdx.x;
    float hv = h[(size_t)n * (H * 64) + t];
    float s = hv * as_w[t];
    float d = hv * ad_w[t];
    #pragma unroll
    for (int off = 32; off > 0; off >>= 1) {
        s += __shfl_down(s, off, 64);
        d += __shfl_down(d, off, 64);
    }
    if ((t & 63) == 0) {
        int head = t >> 6;
        als[n * H + head] = s;
        ald[n * H + head] = d;
    }
}

// ---------------- alpha precompute: segment softmax -> alpha[H][ET] ----------------
template<int H>
__launch_bounds__(256)
__global__ void alpha_kernel(const float* __restrict__ als, const float* __restrict__ ald,
                             const int* __restrict__ row_ptr, const int* __restrict__ col,
                             float* __restrict__ alpha) {
    int lane = threadIdx.x & 63, w = threadIdx.x >> 6;
    int dst = blockIdx.x * 4 + w;
    if (dst >= N_NODES) return;
    int beg = row_ptr[dst], deg = row_ptr[dst + 1] - beg;
    constexpr int ES = 64 / H;
    int i_loc = lane / H, hh = lane % H;
    float ad = ald[dst * H + hh];
    float m = -1e30f, den = 0.f;
    for (int base = 0; base < deg; base += ES) {
        int i = base + i_loc;
        if (i < deg) {
            float e = als[col[beg + i] * H + hh] + ad;
            e = (e > 0.f) ? e : 0.2f * e;
            float nm = fmaxf(m, e);
            den = den * __expf(m - nm) + __expf(e - nm);
            m = nm;
        }
    }
    #pragma unroll
    for (int off = H; off < 64; off <<= 1) {
        float mo = __shfl_xor(m, off, 64);
        float dn = __shfl_xor(den, off, 64);
        float nm = fmaxf(m, mo);
        den = den * __expf(m - nm) + dn * __expf(mo - nm);
        m = nm;
    }
    float rden = 1.f / (den + 1e-16f);
    for (int base = 0; base < deg; base += ES) {
        int i = base + i_loc;
        if (i < deg) {
            float e = als[col[beg + i] * H + hh] + ad;
            e = (e > 0.f) ? e : 0.2f * e;
            alpha[(size_t)hh * ET + beg + i] = __expf(e - m) * rden;
        }
    }
}

// ---------------- channel-sliced aggregation v3 (LDS broadcast) ----------------
template<int CT, int CW, int H, bool RELU, bool SPLIT>
__launch_bounds__(256)
__global__ void agg_v3(const float* __restrict__ h, const float* __restrict__ alpha,
                       const int* __restrict__ row_ptr, const int* __restrict__ col,
                       const float* __restrict__ bias,
                       ushort_t* __restrict__ oh, ushort_t* __restrict__ ol,
                       float* __restrict__ of) {
    constexpr int NS  = CT / CW;         // slices (== H)
    constexpr int LPT = CW / 4;          // lanes per team (16)
    constexpr int TPW = 64 / LPT;        // teams / edges in flight per wave (4)
    static_assert(NS == H, "slice==head mapping");
    __shared__ int   s_src[4][64];
    __shared__ float s_alp[4][64];
    const int nwg = gridDim.x;           // NS * N/4, multiple of 8
    const int q = nwg >> 3;
    int id = blockIdx.x;
    int logical = (id & 7) * q + (id >> 3);
    int slice = logical / (N_NODES / 4);
    int g = logical - slice * (N_NODES / 4);
    int lane = threadIdx.x & 63, w = threadIdx.x >> 6;
    int dst = g * 4 + w;
    int beg = row_ptr[dst], deg = row_ptr[dst + 1] - beg;
    int team = lane / LPT;
    int cc = (lane & (LPT - 1)) * 4;     // channel quad within slice

    const int*   colP = col + beg;
    const float* aP   = alpha + (size_t)slice * ET + beg;
    const float* hS   = h + slice * CW + cc;

    float4 acc = make_float4(0.f, 0.f, 0.f, 0.f);
    for (int base = 0; base < deg; base += 64) {
        int cnt = min(64, deg - base);
        if (lane < cnt) {
            s_src[w][lane] = colP[base + lane];
            s_alp[w][lane] = aP[base + lane];
        }
        for (int i = team; i < cnt; i += TPW) {
            int   s = s_src[w][i];
            float a = s_alp[w][i];
            float4 hv = *(const float4*)&hS[s * CT];     // 32-bit addr math
            acc.x += a * hv.x; acc.y += a * hv.y;
            acc.z += a * hv.z; acc.w += a * hv.w;
        }
    }
    #pragma unroll
    for (int off = LPT; off < 64; off <<= 1) {
        acc.x += __shfl_xor(acc.x, off, 64);
        acc.y += __shfl_xor(acc.y, off, 64);
        acc.z += __shfl_xor(acc.z, off, 64);
        acc.w += __shfl_xor(acc.w, off, 64);
    }
    if (team == 0) {
        int ch = slice * CW + cc;
        float4 bv = *(const float4*)&bias[ch];
        float v0 = acc.x + bv.x, v1 = acc.y + bv.y, v2 = acc.z + bv.z, v3 = acc.w + bv.w;
        if (RELU) {
            v0 = fmaxf(v0, 0.f); v1 = fmaxf(v1, 0.f);
            v2 = fmaxf(v2, 0.f); v3 = fmaxf(v3, 0.f);
        }
        size_t idx = (size_t)dst * CT + ch;
        if (SPLIT) {
            ushort4 h4, l4;
            h4.x = f2bf(v0); l4.x = f2bf(v0 - bf2f(h4.x));
            h4.y = f2bf(v1); l4.y = f2bf(v1 - bf2f(h4.y));
            h4.z = f2bf(v2); l4.z = f2bf(v2 - bf2f(h4.z));
            h4.w = f2bf(v3); l4.w = f2bf(v3 - bf2f(h4.w));
            *(ushort4*)&oh[idx] = h4;
            *(ushort4*)&ol[idx] = l4;
        } else {
            *(float4*)&of[idx] = make_float4(v0, v1, v2, v3);
        }
    }
}

// ---------------- classifier ----------------
__global__ void classifier_kernel(const float* __restrict__ x, const float* __restrict__ wc,
                                  const float* __restrict__ bc, float* __restrict__ out) {
    int n = blockIdx.x * blockDim.x + threadIdx.x;
    if (n >= N_NODES) return;
    float acc[NC] = {bc[0], bc[1], bc[2], bc[3]};
    for (int c = 0; c < 64; ++c) {
        float xv = x[(size_t)n * 64 + c];
        #pragma unroll
        for (int k = 0; k < NC; ++k) acc[k] += xv * wc[c * NC + k];
    }
    #pragma unroll
    for (int k = 0; k < NC; ++k) out[(size_t)n * NC + k] = acc[k];
}

extern "C" void kernel_launch(void* const* d_in, const int* in_sizes, int n_in,
                              void* d_out, int out_size, void* d_ws, size_t ws_size,
                              hipStream_t stream) {
    const float* x   = (const float*)d_in[0];
    const int*   ei  = (const int*)d_in[1];
    const float* w1  = (const float*)d_in[2];
    const float* as1 = (const float*)d_in[3];
    const float* ad1 = (const float*)d_in[4];
    const float* b1  = (const float*)d_in[5];
    const float* w2  = (const float*)d_in[6];
    const float* as2 = (const float*)d_in[7];
    const float* ad2 = (const float*)d_in[8];
    const float* b2  = (const float*)d_in[9];
    const float* w3  = (const float*)d_in[10];
    const float* as3 = (const float*)d_in[11];
    const float* ad3 = (const float*)d_in[12];
    const float* b3  = (const float*)d_in[13];
    const float* wc  = (const float*)d_in[14];
    const float* bc  = (const float*)d_in[15];
    float* out = (float*)d_out;

    char* ws = (char*)d_ws;
    size_t off = 0;
    auto alloc = [&](size_t bytes) -> char* {
        char* p = ws + off;
        off = (off + bytes + 255) & ~(size_t)255;
        return p;
    };

    int* counts  = (int*)alloc(N_NODES * 4);
    int* cursor  = (int*)alloc(N_NODES * 4);
    int* row_ptr = (int*)alloc((N_NODES + 1) * 4);
    int* colidx  = (int*)alloc(ET * 4);
    float* als   = (float*)alloc(N_NODES * 4 * 4);
    float* ald   = (float*)alloc(N_NODES * 4 * 4);
    float* alpha = (float*)alloc((size_t)4 * ET * 4);        // [H][ET]
    float* B0    = (float*)alloc((size_t)N_NODES * HC * 4);

    ushort_t* w1Th = (ushort_t*)alloc((size_t)F_IN * HC * 2);
    ushort_t* w1Tl = (ushort_t*)alloc((size_t)F_IN * HC * 2);
    ushort_t* w2Th = (ushort_t*)alloc((size_t)HC * HC * 2);
    ushort_t* w2Tl = (ushort_t*)alloc((size_t)HC * HC * 2);
    ushort_t* w3Th = (ushort_t*)alloc((size_t)HC * 64 * 2);
    ushort_t* w3Tl = (ushort_t*)alloc((size_t)HC * 64 * 2);
    ushort_t* B1h  = (ushort_t*)alloc((size_t)N_NODES * HC * 2);
    ushort_t* B1l  = (ushort_t*)alloc((size_t)N_NODES * HC * 2);
    float*    B1f  = (float*)alloc((size_t)N_NODES * 64 * 4);

    // ---- CSR build ----
    hipMemsetAsync(counts, 0, N_NODES * sizeof(int), stream);
    int eb = (ET + 255) / 256;
    count_kernel<<<eb, 256, 0, stream>>>(ei, counts);
    scan_kernel<<<1, 1024, 0, stream>>>(counts, row_ptr, cursor);
    scatter_kernel<<<eb, 256, 0, stream>>>(ei, cursor, colidx);

    // ---- weight precision split ----
    split_T<<<(F_IN * HC + 255) / 256, 256, 0, stream>>>(w1, w1Th, w1Tl, F_IN, HC);
    split_T<<<(HC * HC + 255) / 256, 256, 0, stream>>>(w2, w2Th, w2Tl, HC, HC);
    split_T<<<(HC * 64 + 255) / 256, 256, 0, stream>>>(w3, w3Th, w3Tl, HC, 64);

    const int nwg64 = ((N_NODES + 63) / 64) * (HC / 64);     // 313*4 = 1252
    const int nblk_dst = N_NODES / 4;                        // 5000
    // ---- layer 1 (fp32 A, on-the-fly cvt_pk split, dbuf) ----
    gemm_f32a<4><<<nwg64, 256, 0, stream>>>(x, w1Th, w1Tl, B0, N_NODES, F_IN, HC);
    al_kernel<4><<<N_NODES, 256, 0, stream>>>(B0, as1, ad1, als, ald);
    alpha_kernel<4><<<nblk_dst, 256, 0, stream>>>(als, ald, row_ptr, colidx, alpha);
    agg_v3<256, 64, 4, true, true><<<4 * nblk_dst, 256, 0, stream>>>(
        B0, alpha, row_ptr, colidx, b1, B1h, B1l, nullptr);
    // ---- layer 2 ----
    gemm_mfma<4><<<nwg64, 256, 0, stream>>>(B1h, B1l, w2Th, w2Tl, B0, N_NODES, HC, HC);
    al_kernel<4><<<N_NODES, 256, 0, stream>>>(B0, as2, ad2, als, ald);
    alpha_kernel<4><<<nblk_dst, 256, 0, stream>>>(als, ald, row_ptr, colidx, alpha);
    agg_v3<256, 64, 4, true, true><<<4 * nblk_dst, 256, 0, stream>>>(
        B0, alpha, row_ptr, colidx, b2, B1h, B1l, nullptr);
    // ---- layer 3 (H=1, C=64) ----
    const int nwg3 = (N_NODES + 63) / 64;                    // 313
    gemm_mfma<1><<<nwg3, 256, 0, stream>>>(B1h, B1l, w3Th, w3Tl, B0, N_NODES, HC, 64);
    al_kernel<1><<<N_NODES, 64, 0, stream>>>(B0, as3, ad3, als, ald);
    alpha_kernel<1><<<nblk_dst, 256, 0, stream>>>(als, ald, row_ptr, colidx, alpha);
    agg_v3<64, 64, 1, false, false><<<nblk_dst, 256, 0, stream>>>(
        B0, alpha, row_ptr, colidx, b3, nullptr, nullptr, B1f);
    // ---- classifier ----
    classifier_kernel<<<(N_NODES + 255) / 256, 256, 0, stream>>>(B1f, wc, bc, out);
}

// Round 12
// 298.909 us; speedup vs baseline: 1.0560x; 1.0560x over previous
//
#include <hip/hip_runtime.h>

#define N_NODES 20000
#define N_EDGES 320000
#define ET (N_EDGES + N_NODES)   // 340000 edges incl self-loops
#define F_IN 1024
#define HC 256                   // H*C for layers 1,2
#define NC 4

typedef unsigned short ushort_t;
typedef __attribute__((ext_vector_type(8))) short short8;
typedef __attribute__((ext_vector_type(4))) float f32x4;

// bf16 <-> f32 via bit ops (RTNE)
__device__ inline ushort_t f2bf(float f) {
    unsigned u = __float_as_uint(f);
    unsigned r = (u + 0x7fffu + ((u >> 16) & 1u)) >> 16;
    return (ushort_t)r;
}
__device__ inline float bf2f(ushort_t u) {
    return __uint_as_float(((unsigned)u) << 16);
}

// packed f32x2 -> bf16x2 (lo in bits 15:0, hi in bits 31:16), HW RTNE
__device__ inline unsigned cvt_pk_bf16(float lo, float hi) {
    unsigned r;
    asm("v_cvt_pk_bf16_f32 %0, %1, %2" : "=v"(r) : "v"(lo), "v"(hi));
    return r;
}

#define GLOAD16(gp, lp) __builtin_amdgcn_global_load_lds( \
    (const __attribute__((address_space(1))) void*)(gp),  \
    (__attribute__((address_space(3))) void*)(lp), 16, 0, 0)

// ---------------- CSR build ----------------
__global__ void count_kernel(const int* __restrict__ ei, int* __restrict__ counts) {
    int e = blockIdx.x * blockDim.x + threadIdx.x;
    if (e >= ET) return;
    int dst = (e < N_EDGES) ? ei[N_EDGES + e] : (e - N_EDGES);
    atomicAdd(&counts[dst], 1);
}

__global__ void scan_kernel(const int* __restrict__ counts, int* __restrict__ row_ptr,
                            int* __restrict__ cursor) {
    __shared__ int sums[1024];
    int t = threadIdx.x;
    const int per = (N_NODES + 1023) / 1024;
    int b = t * per;
    int e = min(b + per, N_NODES);
    int s = 0;
    for (int i = b; i < e; ++i) s += counts[i];
    sums[t] = s;
    __syncthreads();
    for (int off = 1; off < 1024; off <<= 1) {
        int v = (t >= off) ? sums[t - off] : 0;
        __syncthreads();
        sums[t] += v;
        __syncthreads();
    }
    int run = (t == 0) ? 0 : sums[t - 1];
    for (int i = b; i < e; ++i) {
        row_ptr[i] = run;
        cursor[i]  = run;
        run += counts[i];
    }
    if (t == 0) row_ptr[N_NODES] = ET;
}

__global__ void scatter_kernel(const int* __restrict__ ei, int* __restrict__ cursor,
                               int* __restrict__ col) {
    int e = blockIdx.x * blockDim.x + threadIdx.x;
    if (e >= ET) return;
    int src, dst;
    if (e < N_EDGES) { src = ei[e]; dst = ei[N_EDGES + e]; }
    else             { src = dst = e - N_EDGES; }
    int pos = atomicAdd(&cursor[dst], 1);
    col[pos] = src;
}

// weights: in [K][Nn] fp32 row-major -> hi/lo W^T [Nn][K] bf16
__global__ void split_T(const float* __restrict__ in, ushort_t* __restrict__ hi,
                        ushort_t* __restrict__ lo, int K, int Nn) {
    int idx = blockIdx.x * blockDim.x + threadIdx.x;
    if (idx >= K * Nn) return;
    int k = idx / Nn, n = idx - k * Nn;
    float v = in[idx];
    ushort_t h = f2bf(v);
    hi[(size_t)n * K + k] = h;
    lo[(size_t)n * K + k] = f2bf(v - bf2f(h));
}

// ======== shared epilogue: fused attention-logit reduction ========
// Each block holds head = bn>>6 (BN=64 == one head). Per-thread partial dots
// over its acc frags; 16-lane shfl_xor reduce; LDS combine across wn halves.
#define AL_EPILOGUE()                                                              \
    {                                                                              \
        float asv[NF], adv[NF];                                                    \
        _Pragma("unroll")                                                          \
        for (int j = 0; j < NF; ++j) {                                             \
            int col = bn + wn * SN + j * 16 + (lane & 15);                         \
            asv[j] = as_w[col];                                                    \
            adv[j] = ad_w[col];                                                    \
        }                                                                          \
        float* s_as = (float*)smem;          /* [2][BM] */                         \
        float* s_ad = (float*)smem + 2 * BM;                                       \
        _Pragma("unroll")                                                          \
        for (int i = 0; i < MF; ++i) {                                             \
            _Pragma("unroll")                                                      \
            for (int rr = 0; rr < 4; ++rr) {                                       \
                float ps = 0.f, pd = 0.f;                                          \
                _Pragma("unroll")                                                  \
                for (int j = 0; j < NF; ++j) {                                     \
                    ps += acc[i][j][rr] * asv[j];                                  \
                    pd += acc[i][j][rr] * adv[j];                                  \
                }                                                                  \
                _Pragma("unroll")                                                  \
                for (int o = 1; o < 16; o <<= 1) {                                 \
                    ps += __shfl_xor(ps, o, 64);                                   \
                    pd += __shfl_xor(pd, o, 64);                                   \
                }                                                                  \
                if ((lane & 15) == 0) {                                            \
                    int rl = wm * SM + i * 16 + (lane >> 4) * 4 + rr;              \
                    s_as[wn * BM + rl] = ps;                                       \
                    s_ad[wn * BM + rl] = pd;                                       \
                }                                                                  \
            }                                                                      \
        }                                                                          \
        __syncthreads();                                                           \
        if (t < BM) {                                                              \
            int row = bm + t;                                                      \
            if (row < M) {                                                         \
                int hb = bn >> 6;                                                  \
                als[row * H + hb] = s_as[t] + s_as[BM + t];                        \
                ald[row * H + hb] = s_ad[t] + s_ad[BM + t];                        \
            }                                                                      \
        }                                                                          \
    }

// ---------------- GEMM1: fp32 A, cvt_pk split in-loop, 128x64, fused al ----------------
template<int GY, int H>
__launch_bounds__(256)
__global__ void gemm_f32a(const float* __restrict__ X,
                          const ushort_t* __restrict__ BTh, const ushort_t* __restrict__ BTl,
                          float* __restrict__ C, const float* __restrict__ as_w,
                          const float* __restrict__ ad_w, float* __restrict__ als,
                          float* __restrict__ ald, int M, int K, int NT) {
    constexpr int BM = 128, BN = 64, SM = 64, SN = 32, MF = 4, NF = 2;
    __shared__ __align__(16) char smem[24576];
    char* Ash = smem;            // 8 KB
    char* Asl = smem + 8192;     // 8 KB
    char* Bsh = smem + 16384;    // 4 KB
    char* Bsl = smem + 20480;    // 4 KB

    const int t = threadIdx.x, lane = t & 63, w = t >> 6;
    const int wm = w >> 1, wn = w & 1;
    const int nwg = gridDim.x;
    const int id = blockIdx.x;
    const int q = nwg >> 3, r = nwg & 7;
    const int xcd = id & 7, idx = id >> 3;
    const int logical = (xcd < r ? xcd * (q + 1) : r * (q + 1) + (xcd - r) * q) + idx;
    const int bm = (logical / GY) * BM, bn = (logical % GY) * BN;

    // A staging: 2 row-groups per thread
    const int achk = lane & 3;
    const float* xRow[2]; int aoff[2];
    #pragma unroll
    for (int qq = 0; qq < 2; ++qq) {
        int arow = (w * 2 + qq) * 16 + (lane >> 2);
        int grow = min(bm + arow, M - 1);
        xRow[qq] = X + (size_t)grow * K + achk * 8;
        aoff[qq] = arow * 64 + ((achk ^ ((arow >> 1) & 3)) * 16);
    }
    // B staging (gload_lds, pre-swizzled source)
    const int gchunk = ((lane & 3) ^ ((lane >> 3) & 3)) * 16;
    const int brow = w * 16 + (lane >> 2);
    const size_t gB = (size_t)(bn + brow) * K * 2 + gchunk;
    const int lB = w * 1024;

    const char* Bhb = (const char*)BTh;
    const char* Blb = (const char*)BTl;
    const int c16 = (lane >> 4);

    f32x4 acc[MF][NF];
    #pragma unroll
    for (int i = 0; i < MF; ++i)
        #pragma unroll
        for (int j = 0; j < NF; ++j) acc[i][j] = (f32x4){0.f, 0.f, 0.f, 0.f};

    float4 c0[2], c1[2];
    #pragma unroll
    for (int qq = 0; qq < 2; ++qq) {
        c0[qq] = *(const float4*)(xRow[qq]);
        c1[qq] = *(const float4*)(xRow[qq] + 4);
    }

    for (int k0 = 0; k0 < K; k0 += 32) {
        float4 n0[2], n1[2];
        if (k0 + 32 < K) {
            #pragma unroll
            for (int qq = 0; qq < 2; ++qq) {
                n0[qq] = *(const float4*)(xRow[qq] + k0 + 32);
                n1[qq] = *(const float4*)(xRow[qq] + k0 + 36);
            }
        }
        // convert + write A
        #pragma unroll
        for (int qq = 0; qq < 2; ++qq) {
            float vv[8] = {c0[qq].x, c0[qq].y, c0[qq].z, c0[qq].w,
                           c1[qq].x, c1[qq].y, c1[qq].z, c1[qq].w};
            unsigned hp[4], lp[4];
            #pragma unroll
            for (int j = 0; j < 4; ++j) {
                unsigned h = cvt_pk_bf16(vv[2 * j], vv[2 * j + 1]);
                float h0 = __uint_as_float(h << 16);
                float h1 = __uint_as_float(h & 0xFFFF0000u);
                hp[j] = h;
                lp[j] = cvt_pk_bf16(vv[2 * j] - h0, vv[2 * j + 1] - h1);
            }
            *(uint4*)(Ash + aoff[qq]) = make_uint4(hp[0], hp[1], hp[2], hp[3]);
            *(uint4*)(Asl + aoff[qq]) = make_uint4(lp[0], lp[1], lp[2], lp[3]);
        }
        // B async to LDS
        size_t kb = (size_t)k0 * 2;
        GLOAD16(Bhb + gB + kb, Bsh + lB);
        GLOAD16(Blb + gB + kb, Bsl + lB);
        __syncthreads();
        short8 afh[MF], afl[MF], bfh[NF], bfl[NF];
        #pragma unroll
        for (int i = 0; i < MF; ++i) {
            int row = wm * SM + i * 16 + (lane & 15);
            int off = row * 64 + ((c16 ^ ((row >> 1) & 3)) * 16);
            afh[i] = *(const short8*)(Ash + off);
            afl[i] = *(const short8*)(Asl + off);
        }
        #pragma unroll
        for (int j = 0; j < NF; ++j) {
            int row = wn * SN + j * 16 + (lane & 15);
            int off = row * 64 + ((c16 ^ ((row >> 1) & 3)) * 16);
            bfh[j] = *(const short8*)(Bsh + off);
            bfl[j] = *(const short8*)(Bsl + off);
        }
        #pragma unroll
        for (int i = 0; i < MF; ++i)
            #pragma unroll
            for (int j = 0; j < NF; ++j) {
                acc[i][j] = __builtin_amdgcn_mfma_f32_16x16x32_bf16(afh[i], bfh[j], acc[i][j], 0, 0, 0);
                acc[i][j] = __builtin_amdgcn_mfma_f32_16x16x32_bf16(afh[i], bfl[j], acc[i][j], 0, 0, 0);
                acc[i][j] = __builtin_amdgcn_mfma_f32_16x16x32_bf16(afl[i], bfh[j], acc[i][j], 0, 0, 0);
            }
        __syncthreads();
        #pragma unroll
        for (int qq = 0; qq < 2; ++qq) { c0[qq] = n0[qq]; c1[qq] = n1[qq]; }
    }
    #pragma unroll
    for (int i = 0; i < MF; ++i) {
        int rbase = bm + wm * SM + i * 16 + (lane >> 4) * 4;
        #pragma unroll
        for (int j = 0; j < NF; ++j) {
            int col = bn + wn * SN + j * 16 + (lane & 15);
            #pragma unroll
            for (int rr = 0; rr < 4; ++rr)
                if (rbase + rr < M) C[(size_t)(rbase + rr) * NT + col] = acc[i][j][rr];
        }
    }
    AL_EPILOGUE()
}

// ---------------- split-bf16 MFMA GEMM (bf16 A), 128x64, fused al ----------------
template<int GY, int H>
__launch_bounds__(256)
__global__ void gemm_mfma(const ushort_t* __restrict__ Ah, const ushort_t* __restrict__ Al,
                          const ushort_t* __restrict__ BTh, const ushort_t* __restrict__ BTl,
                          float* __restrict__ C, const float* __restrict__ as_w,
                          const float* __restrict__ ad_w, float* __restrict__ als,
                          float* __restrict__ ald, int M, int K, int NT) {
    constexpr int BM = 128, BN = 64, SM = 64, SN = 32, MF = 4, NF = 2;
    __shared__ __align__(16) char smem[24576];
    char* Ash = smem;            // 8 KB
    char* Asl = smem + 8192;     // 8 KB
    char* Bsh = smem + 16384;    // 4 KB
    char* Bsl = smem + 20480;    // 4 KB

    const int t = threadIdx.x, lane = t & 63, w = t >> 6;
    const int wm = w >> 1, wn = w & 1;
    const int nwg = gridDim.x;
    const int id = blockIdx.x;
    const int q = nwg >> 3, r = nwg & 7;
    const int xcd = id & 7, idx = id >> 3;
    const int logical = (xcd < r ? xcd * (q + 1) : r * (q + 1) + (xcd - r) * q) + idx;
    const int bm = (logical / GY) * BM, bn = (logical % GY) * BN;
    const int gchunk = ((lane & 3) ^ ((lane >> 3) & 3)) * 16;

    size_t gA[2]; int lA[2];
    #pragma unroll
    for (int qq = 0; qq < 2; ++qq) {
        int arow = (w * 2 + qq) * 16 + (lane >> 2);
        int grow = min(bm + arow, M - 1);
        gA[qq] = (size_t)grow * K * 2 + gchunk;
        lA[qq] = (w * 2 + qq) * 1024;
    }
    const int brow = w * 16 + (lane >> 2);
    const size_t gB = (size_t)(bn + brow) * K * 2 + gchunk;
    const int lB = w * 1024;

    const char* Ahb = (const char*)Ah;
    const char* Alb = (const char*)Al;
    const char* Bhb = (const char*)BTh;
    const char* Blb = (const char*)BTl;
    const int c16 = (lane >> 4);

    f32x4 acc[MF][NF];
    #pragma unroll
    for (int i = 0; i < MF; ++i)
        #pragma unroll
        for (int j = 0; j < NF; ++j) acc[i][j] = (f32x4){0.f, 0.f, 0.f, 0.f};

    for (int k0 = 0; k0 < K; k0 += 32) {
        size_t kb = (size_t)k0 * 2;
        #pragma unroll
        for (int qq = 0; qq < 2; ++qq) {
            GLOAD16(Ahb + gA[qq] + kb, Ash + lA[qq]);
            GLOAD16(Alb + gA[qq] + kb, Asl + lA[qq]);
        }
        GLOAD16(Bhb + gB + kb, Bsh + lB);
        GLOAD16(Blb + gB + kb, Bsl + lB);
        __syncthreads();
        short8 afh[MF], afl[MF], bfh[NF], bfl[NF];
        #pragma unroll
        for (int i = 0; i < MF; ++i) {
            int row = wm * SM + i * 16 + (lane & 15);
            int off = row * 64 + ((c16 ^ ((row >> 1) & 3)) * 16);
            afh[i] = *(const short8*)(Ash + off);
            afl[i] = *(const short8*)(Asl + off);
        }
        #pragma unroll
        for (int j = 0; j < NF; ++j) {
            int row = wn * SN + j * 16 + (lane & 15);
            int off = row * 64 + ((c16 ^ ((row >> 1) & 3)) * 16);
            bfh[j] = *(const short8*)(Bsh + off);
            bfl[j] = *(const short8*)(Bsl + off);
        }
        #pragma unroll
        for (int i = 0; i < MF; ++i)
            #pragma unroll
            for (int j = 0; j < NF; ++j) {
                acc[i][j] = __builtin_amdgcn_mfma_f32_16x16x32_bf16(afh[i], bfh[j], acc[i][j], 0, 0, 0);
                acc[i][j] = __builtin_amdgcn_mfma_f32_16x16x32_bf16(afh[i], bfl[j], acc[i][j], 0, 0, 0);
                acc[i][j] = __builtin_amdgcn_mfma_f32_16x16x32_bf16(afl[i], bfh[j], acc[i][j], 0, 0, 0);
            }
        __syncthreads();
    }
    #pragma unroll
    for (int i = 0; i < MF; ++i) {
        int rbase = bm + wm * SM + i * 16 + (lane >> 4) * 4;
        #pragma unroll
        for (int j = 0; j < NF; ++j) {
            int col = bn + wn * SN + j * 16 + (lane & 15);
            #pragma unroll
            for (int rr = 0; rr < 4; ++rr)
                if (rbase + rr < M) C[(size_t)(rbase + rr) * NT + col] = acc[i][j][rr];
        }
    }
    AL_EPILOGUE()
}

// ---------------- alpha precompute: segment softmax -> alpha[H][ET] ----------------
template<int H>
__launch_bounds__(256)
__global__ void alpha_kernel(const float* __restrict__ als, const float* __restrict__ ald,
                             const int* __restrict__ row_ptr, const int* __restrict__ col,
                             float* __restrict__ alpha) {
    int lane = threadIdx.x & 63, w = threadIdx.x >> 6;
    int dst = blockIdx.x * 4 + w;
    if (dst >= N_NODES) return;
    int beg = row_ptr[dst], deg = row_ptr[dst + 1] - beg;
    constexpr int ES = 64 / H;
    int i_loc = lane / H, hh = lane % H;
    float ad = ald[dst * H + hh];
    float m = -1e30f, den = 0.f;
    for (int base = 0; base < deg; base += ES) {
        int i = base + i_loc;
        if (i < deg) {
            float e = als[col[beg + i] * H + hh] + ad;
            e = (e > 0.f) ? e : 0.2f * e;
            float nm = fmaxf(m, e);
            den = den * __expf(m - nm) + __expf(e - nm);
            m = nm;
        }
    }
    #pragma unroll
    for (int off = H; off < 64; off <<= 1) {
        float mo = __shfl_xor(m, off, 64);
        float dn = __shfl_xor(den, off, 64);
        float nm = fmaxf(m, mo);
        den = den * __expf(m - nm) + dn * __expf(mo - nm);
        m = nm;
    }
    float rden = 1.f / (den + 1e-16f);
    for (int base = 0; base < deg; base += ES) {
        int i = base + i_loc;
        if (i < deg) {
            float e = als[col[beg + i] * H + hh] + ad;
            e = (e > 0.f) ? e : 0.2f * e;
            alpha[(size_t)hh * ET + beg + i] = __expf(e - m) * rden;
        }
    }
}

// ---------------- channel-sliced aggregation v3 (LDS broadcast) ----------------
template<int CT, int CW, int H, bool RELU, bool SPLIT>
__launch_bounds__(256)
__global__ void agg_v3(const float* __restrict__ h, const float* __restrict__ alpha,
                       const int* __restrict__ row_ptr, const int* __restrict__ col,
                       const float* __restrict__ bias,
                       ushort_t* __restrict__ oh, ushort_t* __restrict__ ol,
                       float* __restrict__ of) {
    constexpr int NS  = CT / CW;         // slices (== H)
    constexpr int LPT = CW / 4;          // lanes per team (16)
    constexpr int TPW = 64 / LPT;        // teams / edges in flight per wave (4)
    static_assert(NS == H, "slice==head mapping");
    __shared__ int   s_src[4][64];
    __shared__ float s_alp[4][64];
    const int nwg = gridDim.x;           // NS * N/4, multiple of 8
    const int q = nwg >> 3;
    int id = blockIdx.x;
    int logical = (id & 7) * q + (id >> 3);
    int slice = logical / (N_NODES / 4);
    int g = logical - slice * (N_NODES / 4);
    int lane = threadIdx.x & 63, w = threadIdx.x >> 6;
    int dst = g * 4 + w;
    int beg = row_ptr[dst], deg = row_ptr[dst + 1] - beg;
    int team = lane / LPT;
    int cc = (lane & (LPT - 1)) * 4;     // channel quad within slice

    const int*   colP = col + beg;
    const float* aP   = alpha + (size_t)slice * ET + beg;
    const float* hS   = h + slice * CW + cc;

    float4 acc = make_float4(0.f, 0.f, 0.f, 0.f);
    for (int base = 0; base < deg; base += 64) {
        int cnt = min(64, deg - base);
        if (lane < cnt) {
            s_src[w][lane] = colP[base + lane];
            s_alp[w][lane] = aP[base + lane];
        }
        for (int i = team; i < cnt; i += TPW) {
            int   s = s_src[w][i];
            float a = s_alp[w][i];
            float4 hv = *(const float4*)&hS[s * CT];     // 32-bit addr math
            acc.x += a * hv.x; acc.y += a * hv.y;
            acc.z += a * hv.z; acc.w += a * hv.w;
        }
    }
    #pragma unroll
    for (int off = LPT; off < 64; off <<= 1) {
        acc.x += __shfl_xor(acc.x, off, 64);
        acc.y += __shfl_xor(acc.y, off, 64);
        acc.z += __shfl_xor(acc.z, off, 64);
        acc.w += __shfl_xor(acc.w, off, 64);
    }
    if (team == 0) {
        int ch = slice * CW + cc;
        float4 bv = *(const float4*)&bias[ch];
        float v0 = acc.x + bv.x, v1 = acc.y + bv.y, v2 = acc.z + bv.z, v3 = acc.w + bv.w;
        if (RELU) {
            v0 = fmaxf(v0, 0.f); v1 = fmaxf(v1, 0.f);
            v2 = fmaxf(v2, 0.f); v3 = fmaxf(v3, 0.f);
        }
        size_t idx = (size_t)dst * CT + ch;
        if (SPLIT) {
            ushort4 h4, l4;
            h4.x = f2bf(v0); l4.x = f2bf(v0 - bf2f(h4.x));
            h4.y = f2bf(v1); l4.y = f2bf(v1 - bf2f(h4.y));
            h4.z = f2bf(v2); l4.z = f2bf(v2 - bf2f(h4.z));
            h4.w = f2bf(v3); l4.w = f2bf(v3 - bf2f(h4.w));
            *(ushort4*)&oh[idx] = h4;
            *(ushort4*)&ol[idx] = l4;
        } else {
            *(float4*)&of[idx] = make_float4(v0, v1, v2, v3);
        }
    }
}

// ---------------- classifier ----------------
__global__ void classifier_kernel(const float* __restrict__ x, const float* __restrict__ wc,
                                  const float* __restrict__ bc, float* __restrict__ out) {
    int n = blockIdx.x * blockDim.x + threadIdx.x;
    if (n >= N_NODES) return;
    float acc[NC] = {bc[0], bc[1], bc[2], bc[3]};
    for (int c = 0; c < 64; ++c) {
        float xv = x[(size_t)n * 64 + c];
        #pragma unroll
        for (int k = 0; k < NC; ++k) acc[k] += xv * wc[c * NC + k];
    }
    #pragma unroll
    for (int k = 0; k < NC; ++k) out[(size_t)n * NC + k] = acc[k];
}

extern "C" void kernel_launch(void* const* d_in, const int* in_sizes, int n_in,
                              void* d_out, int out_size, void* d_ws, size_t ws_size,
                              hipStream_t stream) {
    const float* x   = (const float*)d_in[0];
    const int*   ei  = (const int*)d_in[1];
    const float* w1  = (const float*)d_in[2];
    const float* as1 = (const float*)d_in[3];
    const float* ad1 = (const float*)d_in[4];
    const float* b1  = (const float*)d_in[5];
    const float* w2  = (const float*)d_in[6];
    const float* as2 = (const float*)d_in[7];
    const float* ad2 = (const float*)d_in[8];
    const float* b2  = (const float*)d_in[9];
    const float* w3  = (const float*)d_in[10];
    const float* as3 = (const float*)d_in[11];
    const float* ad3 = (const float*)d_in[12];
    const float* b3  = (const float*)d_in[13];
    const float* wc  = (const float*)d_in[14];
    const float* bc  = (const float*)d_in[15];
    float* out = (float*)d_out;

    char* ws = (char*)d_ws;
    size_t off = 0;
    auto alloc = [&](size_t bytes) -> char* {
        char* p = ws + off;
        off = (off + bytes + 255) & ~(size_t)255;
        return p;
    };

    int* counts  = (int*)alloc(N_NODES * 4);
    int* cursor  = (int*)alloc(N_NODES * 4);
    int* row_ptr = (int*)alloc((N_NODES + 1) * 4);
    int* colidx  = (int*)alloc(ET * 4);
    float* als   = (float*)alloc(N_NODES * 4 * 4);
    float* ald   = (float*)alloc(N_NODES * 4 * 4);
    float* alpha = (float*)alloc((size_t)4 * ET * 4);        // [H][ET]
    float* B0    = (float*)alloc((size_t)N_NODES * HC * 4);

    ushort_t* w1Th = (ushort_t*)alloc((size_t)F_IN * HC * 2);
    ushort_t* w1Tl = (ushort_t*)alloc((size_t)F_IN * HC * 2);
    ushort_t* w2Th = (ushort_t*)alloc((size_t)HC * HC * 2);
    ushort_t* w2Tl = (ushort_t*)alloc((size_t)HC * HC * 2);
    ushort_t* w3Th = (ushort_t*)alloc((size_t)HC * 64 * 2);
    ushort_t* w3Tl = (ushort_t*)alloc((size_t)HC * 64 * 2);
    ushort_t* B1h  = (ushort_t*)alloc((size_t)N_NODES * HC * 2);
    ushort_t* B1l  = (ushort_t*)alloc((size_t)N_NODES * HC * 2);
    float*    B1f  = (float*)alloc((size_t)N_NODES * 64 * 4);

    // ---- CSR build ----
    hipMemsetAsync(counts, 0, N_NODES * sizeof(int), stream);
    int eb = (ET + 255) / 256;
    count_kernel<<<eb, 256, 0, stream>>>(ei, counts);
    scan_kernel<<<1, 1024, 0, stream>>>(counts, row_ptr, cursor);
    scatter_kernel<<<eb, 256, 0, stream>>>(ei, cursor, colidx);

    // ---- weight precision split ----
    split_T<<<(F_IN * HC + 255) / 256, 256, 0, stream>>>(w1, w1Th, w1Tl, F_IN, HC);
    split_T<<<(HC * HC + 255) / 256, 256, 0, stream>>>(w2, w2Th, w2Tl, HC, HC);
    split_T<<<(HC * 64 + 255) / 256, 256, 0, stream>>>(w3, w3Th, w3Tl, HC, 64);

    const int nwg128 = ((N_NODES + 127) / 128) * (HC / 64);  // 157*4 = 628
    const int nblk_dst = N_NODES / 4;                        // 5000
    // ---- layer 1 (fp32 A, on-the-fly cvt_pk split, fused al) ----
    gemm_f32a<4, 4><<<nwg128, 256, 0, stream>>>(x, w1Th, w1Tl, B0, as1, ad1, als, ald,
                                                N_NODES, F_IN, HC);
    alpha_kernel<4><<<nblk_dst, 256, 0, stream>>>(als, ald, row_ptr, colidx, alpha);
    agg_v3<256, 64, 4, true, true><<<4 * nblk_dst, 256, 0, stream>>>(
        B0, alpha, row_ptr, colidx, b1, B1h, B1l, nullptr);
    // ---- layer 2 ----
    gemm_mfma<4, 4><<<nwg128, 256, 0, stream>>>(B1h, B1l, w2Th, w2Tl, B0, as2, ad2, als, ald,
                                                N_NODES, HC, HC);
    alpha_kernel<4><<<nblk_dst, 256, 0, stream>>>(als, ald, row_ptr, colidx, alpha);
    agg_v3<256, 64, 4, true, true><<<4 * nblk_dst, 256, 0, stream>>>(
        B0, alpha, row_ptr, colidx, b2, B1h, B1l, nullptr);
    // ---- layer 3 (H=1, C=64) ----
    const int nwg3 = (N_NODES + 127) / 128;                  // 157
    gemm_mfma<1, 1><<<nwg3, 256, 0, stream>>>(B1h, B1l, w3Th, w3Tl, B0, as3, ad3, als, ald,
                                              N_NODES, HC, 64);
    alpha_kernel<1><<<nblk_dst, 256, 0, stream>>>(als, ald, row_ptr, colidx, alpha);
    agg_v3<64, 64, 1, false, false><<<nblk_dst, 256, 0, stream>>>(
        B0, alpha, row_ptr, colidx, b3, nullptr, nullptr, B1f);
    // ---- classifier ----
    classifier_kernel<<<(N_NODES + 255) / 256, 256, 0, stream>>>(B1f, wc, bc, out);
}

// Round 13
// 292.231 us; speedup vs baseline: 1.0801x; 1.0229x over previous
//
#include <hip/hip_runtime.h>

#define N_NODES 20000
#define N_EDGES 320000
#define ET (N_EDGES + N_NODES)   // 340000 edges incl self-loops
#define F_IN 1024
#define HC 256                   // H*C for layers 1,2
#define NC 4

typedef unsigned short ushort_t;
typedef __attribute__((ext_vector_type(8))) short short8;
typedef __attribute__((ext_vector_type(4))) float f32x4;

// bf16 <-> f32 via bit ops (RTNE)
__device__ inline ushort_t f2bf(float f) {
    unsigned u = __float_as_uint(f);
    unsigned r = (u + 0x7fffu + ((u >> 16) & 1u)) >> 16;
    return (ushort_t)r;
}
__device__ inline float bf2f(ushort_t u) {
    return __uint_as_float(((unsigned)u) << 16);
}

// packed f32x2 -> bf16x2 (lo in bits 15:0, hi in bits 31:16), HW RTNE
__device__ inline unsigned cvt_pk_bf16(float lo, float hi) {
    unsigned r;
    asm("v_cvt_pk_bf16_f32 %0, %1, %2" : "=v"(r) : "v"(lo), "v"(hi));
    return r;
}

#define GLOAD16(gp, lp) __builtin_amdgcn_global_load_lds( \
    (const __attribute__((address_space(1))) void*)(gp),  \
    (__attribute__((address_space(3))) void*)(lp), 16, 0, 0)

// ---------------- CSR build ----------------
__global__ void count_kernel(const int* __restrict__ ei, int* __restrict__ counts) {
    int e = blockIdx.x * blockDim.x + threadIdx.x;
    if (e >= ET) return;
    int dst = (e < N_EDGES) ? ei[N_EDGES + e] : (e - N_EDGES);
    atomicAdd(&counts[dst], 1);
}

__global__ void scan_kernel(const int* __restrict__ counts, int* __restrict__ row_ptr,
                            int* __restrict__ cursor) {
    __shared__ int sums[1024];
    int t = threadIdx.x;
    const int per = (N_NODES + 1023) / 1024;
    int b = t * per;
    int e = min(b + per, N_NODES);
    int s = 0;
    for (int i = b; i < e; ++i) s += counts[i];
    sums[t] = s;
    __syncthreads();
    for (int off = 1; off < 1024; off <<= 1) {
        int v = (t >= off) ? sums[t - off] : 0;
        __syncthreads();
        sums[t] += v;
        __syncthreads();
    }
    int run = (t == 0) ? 0 : sums[t - 1];
    for (int i = b; i < e; ++i) {
        row_ptr[i] = run;
        cursor[i]  = run;
        run += counts[i];
    }
    if (t == 0) row_ptr[N_NODES] = ET;
}

__global__ void scatter_kernel(const int* __restrict__ ei, int* __restrict__ cursor,
                               int* __restrict__ col) {
    int e = blockIdx.x * blockDim.x + threadIdx.x;
    if (e >= ET) return;
    int src, dst;
    if (e < N_EDGES) { src = ei[e]; dst = ei[N_EDGES + e]; }
    else             { src = dst = e - N_EDGES; }
    int pos = atomicAdd(&cursor[dst], 1);
    col[pos] = src;
}

// weights: in [K][Nn] fp32 row-major -> hi/lo W^T [Nn][K] bf16
__global__ void split_T(const float* __restrict__ in, ushort_t* __restrict__ hi,
                        ushort_t* __restrict__ lo, int K, int Nn) {
    int idx = blockIdx.x * blockDim.x + threadIdx.x;
    if (idx >= K * Nn) return;
    int k = idx / Nn, n = idx - k * Nn;
    float v = in[idx];
    ushort_t h = f2bf(v);
    hi[(size_t)n * K + k] = h;
    lo[(size_t)n * K + k] = f2bf(v - bf2f(h));
}

// ======== shared epilogue: fused attention-logit reduction ========
#define AL_EPILOGUE()                                                              \
    {                                                                              \
        float asv[NF], adv[NF];                                                    \
        _Pragma("unroll")                                                          \
        for (int j = 0; j < NF; ++j) {                                             \
            int col = bn + wn * SN + j * 16 + (lane & 15);                         \
            asv[j] = as_w[col];                                                    \
            adv[j] = ad_w[col];                                                    \
        }                                                                          \
        float* s_as = (float*)smem;          /* [2][BM] */                         \
        float* s_ad = (float*)smem + 2 * BM;                                       \
        _Pragma("unroll")                                                          \
        for (int i = 0; i < MF; ++i) {                                             \
            _Pragma("unroll")                                                      \
            for (int rr = 0; rr < 4; ++rr) {                                       \
                float ps = 0.f, pd = 0.f;                                          \
                _Pragma("unroll")                                                  \
                for (int j = 0; j < NF; ++j) {                                     \
                    ps += acc[i][j][rr] * asv[j];                                  \
                    pd += acc[i][j][rr] * adv[j];                                  \
                }                                                                  \
                _Pragma("unroll")                                                  \
                for (int o = 1; o < 16; o <<= 1) {                                 \
                    ps += __shfl_xor(ps, o, 64);                                   \
                    pd += __shfl_xor(pd, o, 64);                                   \
                }                                                                  \
                if ((lane & 15) == 0) {                                            \
                    int rl = wm * SM + i * 16 + (lane >> 4) * 4 + rr;              \
                    s_as[wn * BM + rl] = ps;                                       \
                    s_ad[wn * BM + rl] = pd;                                       \
                }                                                                  \
            }                                                                      \
        }                                                                          \
        __syncthreads();                                                           \
        if (t < BM) {                                                              \
            int row = bm + t;                                                      \
            if (row < M) {                                                         \
                int hb = bn >> 6;                                                  \
                als[row * H + hb] = s_as[t] + s_as[BM + t];                        \
                ald[row * H + hb] = s_ad[t] + s_ad[BM + t];                        \
            }                                                                      \
        }                                                                          \
    }

// ---------------- GEMM1: fp32 A, cvt_pk split, BK=64, 128x64, fused al ----------------
template<int GY, int H>
__launch_bounds__(256)
__global__ void gemm_f32a(const float* __restrict__ X,
                          const ushort_t* __restrict__ BTh, const ushort_t* __restrict__ BTl,
                          float* __restrict__ C, const float* __restrict__ as_w,
                          const float* __restrict__ ad_w, float* __restrict__ als,
                          float* __restrict__ ald, int M, int K, int NT) {
    constexpr int BM = 128, BN = 64, SM = 64, SN = 32, MF = 4, NF = 2;
    // A-hi: kc*8192 | A-lo: 16384+kc*8192 | B-hi: 32768+kc*4096 | B-lo: 40960+kc*4096
    __shared__ __align__(16) char smem[49152];

    const int t = threadIdx.x, lane = t & 63, w = t >> 6;
    const int wm = w >> 1, wn = w & 1;
    const int nwg = gridDim.x;
    const int id = blockIdx.x;
    const int q = nwg >> 3, r = nwg & 7;
    const int xcd = id & 7, idx = id >> 3;
    const int logical = (xcd < r ? xcd * (q + 1) : r * (q + 1) + (xcd - r) * q) + idx;
    const int bm = (logical / GY) * BM, bn = (logical % GY) * BN;

    const int achk = lane & 3;
    const float* xRow[2]; int aoff[2];
    #pragma unroll
    for (int qq = 0; qq < 2; ++qq) {
        int arow = (w * 2 + qq) * 16 + (lane >> 2);
        int grow = min(bm + arow, M - 1);
        xRow[qq] = X + (size_t)grow * K + achk * 8;
        aoff[qq] = arow * 64 + ((achk ^ ((arow >> 1) & 3)) * 16);
    }
    const int gchunk = ((lane & 3) ^ ((lane >> 3) & 3)) * 16;
    const int brow = w * 16 + (lane >> 2);
    const size_t gB = (size_t)(bn + brow) * K * 2 + gchunk;
    const int lB = w * 1024;

    const char* Bhb = (const char*)BTh;
    const char* Blb = (const char*)BTl;
    const int c16 = (lane >> 4);
    const int NTs = K / 64;

    f32x4 acc[MF][NF];
    #pragma unroll
    for (int i = 0; i < MF; ++i)
        #pragma unroll
        for (int j = 0; j < NF; ++j) acc[i][j] = (f32x4){0.f, 0.f, 0.f, 0.f};

    float4 cur0[2][2], cur1[2][2], nxt0[2][2], nxt1[2][2];   // [qq][kc]
    #pragma unroll
    for (int qq = 0; qq < 2; ++qq)
        #pragma unroll
        for (int kc = 0; kc < 2; ++kc) {
            cur0[qq][kc] = *(const float4*)(xRow[qq] + kc * 32);
            cur1[qq][kc] = *(const float4*)(xRow[qq] + kc * 32 + 4);
        }

    for (int ts = 0; ts < NTs; ++ts) {
        // B async to LDS (both k-chunks), issued first
        size_t kb = (size_t)ts * 128;
        #pragma unroll
        for (int kc = 0; kc < 2; ++kc) {
            GLOAD16(Bhb + gB + kb + kc * 64, smem + 32768 + kc * 4096 + lB);
            GLOAD16(Blb + gB + kb + kc * 64, smem + 40960 + kc * 4096 + lB);
        }
        // prefetch next iter's A regs
        if (ts + 1 < NTs) {
            #pragma unroll
            for (int qq = 0; qq < 2; ++qq)
                #pragma unroll
                for (int kc = 0; kc < 2; ++kc) {
                    nxt0[qq][kc] = *(const float4*)(xRow[qq] + (ts + 1) * 64 + kc * 32);
                    nxt1[qq][kc] = *(const float4*)(xRow[qq] + (ts + 1) * 64 + kc * 32 + 4);
                }
        }
        // convert + write current A
        #pragma unroll
        for (int qq = 0; qq < 2; ++qq)
            #pragma unroll
            for (int kc = 0; kc < 2; ++kc) {
                float vv[8] = {cur0[qq][kc].x, cur0[qq][kc].y, cur0[qq][kc].z, cur0[qq][kc].w,
                               cur1[qq][kc].x, cur1[qq][kc].y, cur1[qq][kc].z, cur1[qq][kc].w};
                unsigned hp[4], lp[4];
                #pragma unroll
                for (int j = 0; j < 4; ++j) {
                    unsigned h = cvt_pk_bf16(vv[2 * j], vv[2 * j + 1]);
                    float h0 = __uint_as_float(h << 16);
                    float h1 = __uint_as_float(h & 0xFFFF0000u);
                    hp[j] = h;
                    lp[j] = cvt_pk_bf16(vv[2 * j] - h0, vv[2 * j + 1] - h1);
                }
                *(uint4*)(smem + kc * 8192 + aoff[qq])         = make_uint4(hp[0], hp[1], hp[2], hp[3]);
                *(uint4*)(smem + 16384 + kc * 8192 + aoff[qq]) = make_uint4(lp[0], lp[1], lp[2], lp[3]);
            }
        __syncthreads();
        #pragma unroll
        for (int kc = 0; kc < 2; ++kc) {
            short8 afh[MF], afl[MF], bfh[NF], bfl[NF];
            #pragma unroll
            for (int i = 0; i < MF; ++i) {
                int row = wm * SM + i * 16 + (lane & 15);
                int off = row * 64 + ((c16 ^ ((row >> 1) & 3)) * 16);
                afh[i] = *(const short8*)(smem + kc * 8192 + off);
                afl[i] = *(const short8*)(smem + 16384 + kc * 8192 + off);
            }
            #pragma unroll
            for (int j = 0; j < NF; ++j) {
                int row = wn * SN + j * 16 + (lane & 15);
                int off = row * 64 + ((c16 ^ ((row >> 1) & 3)) * 16);
                bfh[j] = *(const short8*)(smem + 32768 + kc * 4096 + off);
                bfl[j] = *(const short8*)(smem + 40960 + kc * 4096 + off);
            }
            #pragma unroll
            for (int i = 0; i < MF; ++i)
                #pragma unroll
                for (int j = 0; j < NF; ++j) {
                    acc[i][j] = __builtin_amdgcn_mfma_f32_16x16x32_bf16(afh[i], bfh[j], acc[i][j], 0, 0, 0);
                    acc[i][j] = __builtin_amdgcn_mfma_f32_16x16x32_bf16(afh[i], bfl[j], acc[i][j], 0, 0, 0);
                    acc[i][j] = __builtin_amdgcn_mfma_f32_16x16x32_bf16(afl[i], bfh[j], acc[i][j], 0, 0, 0);
                }
        }
        __syncthreads();
        #pragma unroll
        for (int qq = 0; qq < 2; ++qq)
            #pragma unroll
            for (int kc = 0; kc < 2; ++kc) { cur0[qq][kc] = nxt0[qq][kc]; cur1[qq][kc] = nxt1[qq][kc]; }
    }
    #pragma unroll
    for (int i = 0; i < MF; ++i) {
        int rbase = bm + wm * SM + i * 16 + (lane >> 4) * 4;
        #pragma unroll
        for (int j = 0; j < NF; ++j) {
            int col = bn + wn * SN + j * 16 + (lane & 15);
            #pragma unroll
            for (int rr = 0; rr < 4; ++rr)
                if (rbase + rr < M) C[(size_t)(rbase + rr) * NT + col] = acc[i][j][rr];
        }
    }
    AL_EPILOGUE()
}

// ---------------- split-bf16 MFMA GEMM (bf16 A), BK=64, fused al ----------------
template<int BMT, int GY, int H>
__launch_bounds__(256)
__global__ void gemm_mfma(const ushort_t* __restrict__ Ah, const ushort_t* __restrict__ Al,
                          const ushort_t* __restrict__ BTh, const ushort_t* __restrict__ BTl,
                          float* __restrict__ C, const float* __restrict__ as_w,
                          const float* __restrict__ ad_w, float* __restrict__ als,
                          float* __restrict__ ald, int M, int K, int NT) {
    constexpr int BM = BMT, BN = 64, SM = BM / 2, SN = 32, MF = SM / 16, NF = 2;
    constexpr int AQ = BM / 64;            // A gloads per wave per k-chunk
    constexpr int ASZ = BM * 64;           // bytes per A chunk
    // Ah: kc*ASZ | Al: 2*ASZ+kc*ASZ | Bh: 4*ASZ+kc*4096 | Bl: 4*ASZ+8192+kc*4096
    __shared__ __align__(16) char smem[4 * ASZ + 16384];

    const int t = threadIdx.x, lane = t & 63, w = t >> 6;
    const int wm = w >> 1, wn = w & 1;
    const int nwg = gridDim.x;
    const int id = blockIdx.x;
    const int q = nwg >> 3, r = nwg & 7;
    const int xcd = id & 7, idx = id >> 3;
    const int logical = (xcd < r ? xcd * (q + 1) : r * (q + 1) + (xcd - r) * q) + idx;
    const int bm = (logical / GY) * BM, bn = (logical % GY) * BN;
    const int gchunk = ((lane & 3) ^ ((lane >> 3) & 3)) * 16;

    size_t gA[AQ]; int lA[AQ];
    #pragma unroll
    for (int qq = 0; qq < AQ; ++qq) {
        int inst = w * AQ + qq;
        int arow = inst * 16 + (lane >> 2);
        int grow = min(bm + arow, M - 1);
        gA[qq] = (size_t)grow * K * 2 + gchunk;
        lA[qq] = inst * 1024;
    }
    const int brow = w * 16 + (lane >> 2);
    const size_t gB = (size_t)(bn + brow) * K * 2 + gchunk;
    const int lB = w * 1024;

    const char* Ahb = (const char*)Ah;
    const char* Alb = (const char*)Al;
    const char* Bhb = (const char*)BTh;
    const char* Blb = (const char*)BTl;
    const int c16 = (lane >> 4);
    const int NTs = K / 64;

    f32x4 acc[MF][NF];
    #pragma unroll
    for (int i = 0; i < MF; ++i)
        #pragma unroll
        for (int j = 0; j < NF; ++j) acc[i][j] = (f32x4){0.f, 0.f, 0.f, 0.f};

    for (int ts = 0; ts < NTs; ++ts) {
        size_t kb = (size_t)ts * 128;
        #pragma unroll
        for (int kc = 0; kc < 2; ++kc) {
            #pragma unroll
            for (int qq = 0; qq < AQ; ++qq) {
                GLOAD16(Ahb + gA[qq] + kb + kc * 64, smem + kc * ASZ + lA[qq]);
                GLOAD16(Alb + gA[qq] + kb + kc * 64, smem + 2 * ASZ + kc * ASZ + lA[qq]);
            }
            GLOAD16(Bhb + gB + kb + kc * 64, smem + 4 * ASZ + kc * 4096 + lB);
            GLOAD16(Blb + gB + kb + kc * 64, smem + 4 * ASZ + 8192 + kc * 4096 + lB);
        }
        __syncthreads();
        #pragma unroll
        for (int kc = 0; kc < 2; ++kc) {
            short8 afh[MF], afl[MF], bfh[NF], bfl[NF];
            #pragma unroll
            for (int i = 0; i < MF; ++i) {
                int row = wm * SM + i * 16 + (lane & 15);
                int off = row * 64 + ((c16 ^ ((row >> 1) & 3)) * 16);
                afh[i] = *(const short8*)(smem + kc * ASZ + off);
                afl[i] = *(const short8*)(smem + 2 * ASZ + kc * ASZ + off);
            }
            #pragma unroll
            for (int j = 0; j < NF; ++j) {
                int row = wn * SN + j * 16 + (lane & 15);
                int off = row * 64 + ((c16 ^ ((row >> 1) & 3)) * 16);
                bfh[j] = *(const short8*)(smem + 4 * ASZ + kc * 4096 + off);
                bfl[j] = *(const short8*)(smem + 4 * ASZ + 8192 + kc * 4096 + off);
            }
            #pragma unroll
            for (int i = 0; i < MF; ++i)
                #pragma unroll
                for (int j = 0; j < NF; ++j) {
                    acc[i][j] = __builtin_amdgcn_mfma_f32_16x16x32_bf16(afh[i], bfh[j], acc[i][j], 0, 0, 0);
                    acc[i][j] = __builtin_amdgcn_mfma_f32_16x16x32_bf16(afh[i], bfl[j], acc[i][j], 0, 0, 0);
                    acc[i][j] = __builtin_amdgcn_mfma_f32_16x16x32_bf16(afl[i], bfh[j], acc[i][j], 0, 0, 0);
                }
        }
        __syncthreads();
    }
    #pragma unroll
    for (int i = 0; i < MF; ++i) {
        int rbase = bm + wm * SM + i * 16 + (lane >> 4) * 4;
        #pragma unroll
        for (int j = 0; j < NF; ++j) {
            int col = bn + wn * SN + j * 16 + (lane & 15);
            #pragma unroll
            for (int rr = 0; rr < 4; ++rr)
                if (rbase + rr < M) C[(size_t)(rbase + rr) * NT + col] = acc[i][j][rr];
        }
    }
    AL_EPILOGUE()
}

// ---------------- alpha precompute: segment softmax -> alpha[H][ET] ----------------
template<int H>
__launch_bounds__(256)
__global__ void alpha_kernel(const float* __restrict__ als, const float* __restrict__ ald,
                             const int* __restrict__ row_ptr, const int* __restrict__ col,
                             float* __restrict__ alpha) {
    int lane = threadIdx.x & 63, w = threadIdx.x >> 6;
    int dst = blockIdx.x * 4 + w;
    if (dst >= N_NODES) return;
    int beg = row_ptr[dst], deg = row_ptr[dst + 1] - beg;
    constexpr int ES = 64 / H;
    int i_loc = lane / H, hh = lane % H;
    float ad = ald[dst * H + hh];
    float m = -1e30f, den = 0.f;
    for (int base = 0; base < deg; base += ES) {
        int i = base + i_loc;
        if (i < deg) {
            float e = als[col[beg + i] * H + hh] + ad;
            e = (e > 0.f) ? e : 0.2f * e;
            float nm = fmaxf(m, e);
            den = den * __expf(m - nm) + __expf(e - nm);
            m = nm;
        }
    }
    #pragma unroll
    for (int off = H; off < 64; off <<= 1) {
        float mo = __shfl_xor(m, off, 64);
        float dn = __shfl_xor(den, off, 64);
        float nm = fmaxf(m, mo);
        den = den * __expf(m - nm) + dn * __expf(mo - nm);
        m = nm;
    }
    float rden = 1.f / (den + 1e-16f);
    for (int base = 0; base < deg; base += ES) {
        int i = base + i_loc;
        if (i < deg) {
            float e = als[col[beg + i] * H + hh] + ad;
            e = (e > 0.f) ? e : 0.2f * e;
            alpha[(size_t)hh * ET + beg + i] = __expf(e - m) * rden;
        }
    }
}

// ---------------- channel-sliced aggregation v3 (LDS broadcast) ----------------
template<int CT, int CW, int H, bool RELU, bool SPLIT>
__launch_bounds__(256)
__global__ void agg_v3(const float* __restrict__ h, const float* __restrict__ alpha,
                       const int* __restrict__ row_ptr, const int* __restrict__ col,
                       const float* __restrict__ bias,
                       ushort_t* __restrict__ oh, ushort_t* __restrict__ ol,
                       float* __restrict__ of) {
    constexpr int NS  = CT / CW;         // slices (== H)
    constexpr int LPT = CW / 4;          // lanes per team (16)
    constexpr int TPW = 64 / LPT;        // teams / edges in flight per wave (4)
    static_assert(NS == H, "slice==head mapping");
    __shared__ int   s_src[4][64];
    __shared__ float s_alp[4][64];
    const int nwg = gridDim.x;           // NS * N/4, multiple of 8
    const int q = nwg >> 3;
    int id = blockIdx.x;
    int logical = (id & 7) * q + (id >> 3);
    int slice = logical / (N_NODES / 4);
    int g = logical - slice * (N_NODES / 4);
    int lane = threadIdx.x & 63, w = threadIdx.x >> 6;
    int dst = g * 4 + w;
    int beg = row_ptr[dst], deg = row_ptr[dst + 1] - beg;
    int team = lane / LPT;
    int cc = (lane & (LPT - 1)) * 4;     // channel quad within slice

    const int*   colP = col + beg;
    const float* aP   = alpha + (size_t)slice * ET + beg;
    const float* hS   = h + slice * CW + cc;

    float4 acc = make_float4(0.f, 0.f, 0.f, 0.f);
    for (int base = 0; base < deg; base += 64) {
        int cnt = min(64, deg - base);
        if (lane < cnt) {
            s_src[w][lane] = colP[base + lane];
            s_alp[w][lane] = aP[base + lane];
        }
        for (int i = team; i < cnt; i += TPW) {
            int   s = s_src[w][i];
            float a = s_alp[w][i];
            float4 hv = *(const float4*)&hS[s * CT];     // 32-bit addr math
            acc.x += a * hv.x; acc.y += a * hv.y;
            acc.z += a * hv.z; acc.w += a * hv.w;
        }
    }
    #pragma unroll
    for (int off = LPT; off < 64; off <<= 1) {
        acc.x += __shfl_xor(acc.x, off, 64);
        acc.y += __shfl_xor(acc.y, off, 64);
        acc.z += __shfl_xor(acc.z, off, 64);
        acc.w += __shfl_xor(acc.w, off, 64);
    }
    if (team == 0) {
        int ch = slice * CW + cc;
        float4 bv = *(const float4*)&bias[ch];
        float v0 = acc.x + bv.x, v1 = acc.y + bv.y, v2 = acc.z + bv.z, v3 = acc.w + bv.w;
        if (RELU) {
            v0 = fmaxf(v0, 0.f); v1 = fmaxf(v1, 0.f);
            v2 = fmaxf(v2, 0.f); v3 = fmaxf(v3, 0.f);
        }
        size_t idx = (size_t)dst * CT + ch;
        if (SPLIT) {
            ushort4 h4, l4;
            h4.x = f2bf(v0); l4.x = f2bf(v0 - bf2f(h4.x));
            h4.y = f2bf(v1); l4.y = f2bf(v1 - bf2f(h4.y));
            h4.z = f2bf(v2); l4.z = f2bf(v2 - bf2f(h4.z));
            h4.w = f2bf(v3); l4.w = f2bf(v3 - bf2f(h4.w));
            *(ushort4*)&oh[idx] = h4;
            *(ushort4*)&ol[idx] = l4;
        } else {
            *(float4*)&of[idx] = make_float4(v0, v1, v2, v3);
        }
    }
}

// ---------------- classifier ----------------
__global__ void classifier_kernel(const float* __restrict__ x, const float* __restrict__ wc,
                                  const float* __restrict__ bc, float* __restrict__ out) {
    int n = blockIdx.x * blockDim.x + threadIdx.x;
    if (n >= N_NODES) return;
    float acc[NC] = {bc[0], bc[1], bc[2], bc[3]};
    for (int c = 0; c < 64; ++c) {
        float xv = x[(size_t)n * 64 + c];
        #pragma unroll
        for (int k = 0; k < NC; ++k) acc[k] += xv * wc[c * NC + k];
    }
    #pragma unroll
    for (int k = 0; k < NC; ++k) out[(size_t)n * NC + k] = acc[k];
}

extern "C" void kernel_launch(void* const* d_in, const int* in_sizes, int n_in,
                              void* d_out, int out_size, void* d_ws, size_t ws_size,
                              hipStream_t stream) {
    const float* x   = (const float*)d_in[0];
    const int*   ei  = (const int*)d_in[1];
    const float* w1  = (const float*)d_in[2];
    const float* as1 = (const float*)d_in[3];
    const float* ad1 = (const float*)d_in[4];
    const float* b1  = (const float*)d_in[5];
    const float* w2  = (const float*)d_in[6];
    const float* as2 = (const float*)d_in[7];
    const float* ad2 = (const float*)d_in[8];
    const float* b2  = (const float*)d_in[9];
    const float* w3  = (const float*)d_in[10];
    const float* as3 = (const float*)d_in[11];
    const float* ad3 = (const float*)d_in[12];
    const float* b3  = (const float*)d_in[13];
    const float* wc  = (const float*)d_in[14];
    const float* bc  = (const float*)d_in[15];
    float* out = (float*)d_out;

    char* ws = (char*)d_ws;
    size_t off = 0;
    auto alloc = [&](size_t bytes) -> char* {
        char* p = ws + off;
        off = (off + bytes + 255) & ~(size_t)255;
        return p;
    };

    int* counts  = (int*)alloc(N_NODES * 4);
    int* cursor  = (int*)alloc(N_NODES * 4);
    int* row_ptr = (int*)alloc((N_NODES + 1) * 4);
    int* colidx  = (int*)alloc(ET * 4);
    float* als   = (float*)alloc(N_NODES * 4 * 4);
    float* ald   = (float*)alloc(N_NODES * 4 * 4);
    float* alpha = (float*)alloc((size_t)4 * ET * 4);        // [H][ET]
    float* B0    = (float*)alloc((size_t)N_NODES * HC * 4);

    ushort_t* w1Th = (ushort_t*)alloc((size_t)F_IN * HC * 2);
    ushort_t* w1Tl = (ushort_t*)alloc((size_t)F_IN * HC * 2);
    ushort_t* w2Th = (ushort_t*)alloc((size_t)HC * HC * 2);
    ushort_t* w2Tl = (ushort_t*)alloc((size_t)HC * HC * 2);
    ushort_t* w3Th = (ushort_t*)alloc((size_t)HC * 64 * 2);
    ushort_t* w3Tl = (ushort_t*)alloc((size_t)HC * 64 * 2);
    ushort_t* B1h  = (ushort_t*)alloc((size_t)N_NODES * HC * 2);
    ushort_t* B1l  = (ushort_t*)alloc((size_t)N_NODES * HC * 2);
    float*    B1f  = (float*)alloc((size_t)N_NODES * 64 * 4);

    // ---- CSR build ----
    hipMemsetAsync(counts, 0, N_NODES * sizeof(int), stream);
    int eb = (ET + 255) / 256;
    count_kernel<<<eb, 256, 0, stream>>>(ei, counts);
    scan_kernel<<<1, 1024, 0, stream>>>(counts, row_ptr, cursor);
    scatter_kernel<<<eb, 256, 0, stream>>>(ei, cursor, colidx);

    // ---- weight precision split ----
    split_T<<<(F_IN * HC + 255) / 256, 256, 0, stream>>>(w1, w1Th, w1Tl, F_IN, HC);
    split_T<<<(HC * HC + 255) / 256, 256, 0, stream>>>(w2, w2Th, w2Tl, HC, HC);
    split_T<<<(HC * 64 + 255) / 256, 256, 0, stream>>>(w3, w3Th, w3Tl, HC, 64);

    const int nwg128 = ((N_NODES + 127) / 128) * (HC / 64);  // 157*4 = 628
    const int nblk_dst = N_NODES / 4;                        // 5000
    // ---- layer 1 (fp32 A, cvt_pk split, BK=64, fused al) ----
    gemm_f32a<4, 4><<<nwg128, 256, 0, stream>>>(x, w1Th, w1Tl, B0, as1, ad1, als, ald,
                                                N_NODES, F_IN, HC);
    alpha_kernel<4><<<nblk_dst, 256, 0, stream>>>(als, ald, row_ptr, colidx, alpha);
    agg_v3<256, 64, 4, true, true><<<4 * nblk_dst, 256, 0, stream>>>(
        B0, alpha, row_ptr, colidx, b1, B1h, B1l, nullptr);
    // ---- layer 2 ----
    gemm_mfma<128, 4, 4><<<nwg128, 256, 0, stream>>>(B1h, B1l, w2Th, w2Tl, B0, as2, ad2,
                                                     als, ald, N_NODES, HC, HC);
    alpha_kernel<4><<<nblk_dst, 256, 0, stream>>>(als, ald, row_ptr, colidx, alpha);
    agg_v3<256, 64, 4, true, true><<<4 * nblk_dst, 256, 0, stream>>>(
        B0, alpha, row_ptr, colidx, b2, B1h, B1l, nullptr);
    // ---- layer 3 (H=1, C=64), BM=64 -> grid 313 ----
    const int nwg3 = (N_NODES + 63) / 64;                    // 313
    gemm_mfma<64, 1, 1><<<nwg3, 256, 0, stream>>>(B1h, B1l, w3Th, w3Tl, B0, as3, ad3,
                                                  als, ald, N_NODES, HC, 64);
    alpha_kernel<1><<<nblk_dst, 256, 0, stream>>>(als, ald, row_ptr, colidx, alpha);
    agg_v3<64, 64, 1, false, false><<<nblk_dst, 256, 0, stream>>>(
        B0, alpha, row_ptr, colidx, b3, nullptr, nullptr, B1f);
    // ---- classifier ----
    classifier_kernel<<<(N_NODES + 255) / 256, 256, 0, stream>>>(B1f, wc, bc, out);
}

// Round 14
// 281.967 us; speedup vs baseline: 1.1195x; 1.0364x over previous
//
#include <hip/hip_runtime.h>

#define N_NODES 20000
#define N_EDGES 320000
#define ET (N_EDGES + N_NODES)   // 340000 edges incl self-loops
#define F_IN 1024
#define HC 256                   // H*C for layers 1,2
#define NC 4

typedef unsigned short ushort_t;
typedef __attribute__((ext_vector_type(8))) short short8;
typedef __attribute__((ext_vector_type(4))) float f32x4;

// bf16 <-> f32 via bit ops (RTNE)
__device__ inline ushort_t f2bf(float f) {
    unsigned u = __float_as_uint(f);
    unsigned r = (u + 0x7fffu + ((u >> 16) & 1u)) >> 16;
    return (ushort_t)r;
}
__device__ inline float bf2f(ushort_t u) {
    return __uint_as_float(((unsigned)u) << 16);
}

// packed f32x2 -> bf16x2, HW RTNE
__device__ inline unsigned cvt_pk_bf16(float lo, float hi) {
    unsigned r;
    asm("v_cvt_pk_bf16_f32 %0, %1, %2" : "=v"(r) : "v"(lo), "v"(hi));
    return r;
}

#define GLOAD16(gp, lp) __builtin_amdgcn_global_load_lds( \
    (const __attribute__((address_space(1))) void*)(gp),  \
    (__attribute__((address_space(3))) void*)(lp), 16, 0, 0)

// ---------------- CSR build ----------------
__global__ void count_kernel(const int* __restrict__ ei, int* __restrict__ counts) {
    int e = blockIdx.x * blockDim.x + threadIdx.x;
    if (e >= ET) return;
    int dst = (e < N_EDGES) ? ei[N_EDGES + e] : (e - N_EDGES);
    atomicAdd(&counts[dst], 1);
}

__global__ void scan_kernel(const int* __restrict__ counts, int* __restrict__ row_ptr,
                            int* __restrict__ cursor) {
    __shared__ int sums[1024];
    int t = threadIdx.x;
    const int per = (N_NODES + 1023) / 1024;
    int b = t * per;
    int e = min(b + per, N_NODES);
    int s = 0;
    for (int i = b; i < e; ++i) s += counts[i];
    sums[t] = s;
    __syncthreads();
    for (int off = 1; off < 1024; off <<= 1) {
        int v = (t >= off) ? sums[t - off] : 0;
        __syncthreads();
        sums[t] += v;
        __syncthreads();
    }
    int run = (t == 0) ? 0 : sums[t - 1];
    for (int i = b; i < e; ++i) {
        row_ptr[i] = run;
        cursor[i]  = run;
        run += counts[i];
    }
    if (t == 0) row_ptr[N_NODES] = ET;
}

__global__ void scatter_kernel(const int* __restrict__ ei, int* __restrict__ cursor,
                               int* __restrict__ col) {
    int e = blockIdx.x * blockDim.x + threadIdx.x;
    if (e >= ET) return;
    int src, dst;
    if (e < N_EDGES) { src = ei[e]; dst = ei[N_EDGES + e]; }
    else             { src = dst = e - N_EDGES; }
    int pos = atomicAdd(&cursor[dst], 1);
    col[pos] = src;
}

// weights: in [K][Nn] fp32 row-major -> hi/lo W^T [Nn][K] bf16
__global__ void split_T(const float* __restrict__ in, ushort_t* __restrict__ hi,
                        ushort_t* __restrict__ lo, int K, int Nn) {
    int idx = blockIdx.x * blockDim.x + threadIdx.x;
    if (idx >= K * Nn) return;
    int k = idx / Nn, n = idx - k * Nn;
    float v = in[idx];
    ushort_t h = f2bf(v);
    hi[(size_t)n * K + k] = h;
    lo[(size_t)n * K + k] = f2bf(v - bf2f(h));
}

// ======== fused attention-logit epilogue (used by gemm_mfma) ========
#define AL_EPILOGUE()                                                              \
    {                                                                              \
        float asv[NF], adv[NF];                                                    \
        _Pragma("unroll")                                                          \
        for (int j = 0; j < NF; ++j) {                                             \
            int col = bn + wn * SN + j * 16 + (lane & 15);                         \
            asv[j] = as_w[col];                                                    \
            adv[j] = ad_w[col];                                                    \
        }                                                                          \
        float* s_as = (float*)smem;          /* [2][BM] */                         \
        float* s_ad = (float*)smem + 2 * BM;                                       \
        _Pragma("unroll")                                                          \
        for (int i = 0; i < MF; ++i) {                                             \
            _Pragma("unroll")                                                      \
            for (int rr = 0; rr < 4; ++rr) {                                       \
                float ps = 0.f, pd = 0.f;                                          \
                _Pragma("unroll")                                                  \
                for (int j = 0; j < NF; ++j) {                                     \
                    ps += acc[i][j][rr] * asv[j];                                  \
                    pd += acc[i][j][rr] * adv[j];                                  \
                }                                                                  \
                _Pragma("unroll")                                                  \
                for (int o = 1; o < 16; o <<= 1) {                                 \
                    ps += __shfl_xor(ps, o, 64);                                   \
                    pd += __shfl_xor(pd, o, 64);                                   \
                }                                                                  \
                if ((lane & 15) == 0) {                                            \
                    int rl = wm * SM + i * 16 + (lane >> 4) * 4 + rr;              \
                    s_as[wn * BM + rl] = ps;                                       \
                    s_ad[wn * BM + rl] = pd;                                       \
                }                                                                  \
            }                                                                      \
        }                                                                          \
        __syncthreads();                                                           \
        if (t < BM) {                                                              \
            int row = bm + t;                                                      \
            if (row < M) {                                                         \
                int hb = bn >> 6;                                                  \
                als[row * H + hb] = s_as[t] + s_as[BM + t];                        \
                ald[row * H + hb] = s_ad[t] + s_ad[BM + t];                        \
            }                                                                      \
        }                                                                          \
    }

// ---------------- GEMM1: fp32 A, cvt_pk split, BK=64, split-K deterministic ----------------
// grid = 2 * nwg_half; ks = logical / nwg_half picks K-half and output buffer.
template<int GY>
__launch_bounds__(256)
__global__ void gemm_f32a_ks(const float* __restrict__ X,
                             const ushort_t* __restrict__ BTh, const ushort_t* __restrict__ BTl,
                             float* __restrict__ Cp0, float* __restrict__ Cp1,
                             int M, int K, int NT) {
    constexpr int BM = 128, BN = 64, SM = 64, SN = 32, MF = 4, NF = 2;
    __shared__ __align__(16) char smem[49152];

    const int t = threadIdx.x, lane = t & 63, w = t >> 6;
    const int wm = w >> 1, wn = w & 1;
    const int nwg = gridDim.x;
    const int id = blockIdx.x;
    const int q = nwg >> 3, r = nwg & 7;
    const int xcd = id & 7, idx = id >> 3;
    const int logical = (xcd < r ? xcd * (q + 1) : r * (q + 1) + (xcd - r) * q) + idx;
    const int nwg_half = nwg >> 1;
    const int ks = logical / nwg_half;
    const int rem = logical - ks * nwg_half;
    const int bm = (rem / GY) * BM, bn = (rem % GY) * BN;
    const int kbase = ks * (K >> 1);              // element offset
    float* Cp = ks ? Cp1 : Cp0;

    const int achk = lane & 3;
    const float* xRow[2]; int aoff[2];
    #pragma unroll
    for (int qq = 0; qq < 2; ++qq) {
        int arow = (w * 2 + qq) * 16 + (lane >> 2);
        int grow = min(bm + arow, M - 1);
        xRow[qq] = X + (size_t)grow * K + kbase + achk * 8;
        aoff[qq] = arow * 64 + ((achk ^ ((arow >> 1) & 3)) * 16);
    }
    const int gchunk = ((lane & 3) ^ ((lane >> 3) & 3)) * 16;
    const int brow = w * 16 + (lane >> 2);
    const size_t gB = (size_t)(bn + brow) * K * 2 + (size_t)kbase * 2 + gchunk;
    const int lB = w * 1024;

    const char* Bhb = (const char*)BTh;
    const char* Blb = (const char*)BTl;
    const int c16 = (lane >> 4);
    const int NTs = K >> 7;                        // (K/2)/64 tiles per half

    f32x4 acc[MF][NF];
    #pragma unroll
    for (int i = 0; i < MF; ++i)
        #pragma unroll
        for (int j = 0; j < NF; ++j) acc[i][j] = (f32x4){0.f, 0.f, 0.f, 0.f};

    float4 cur0[2][2], cur1[2][2], nxt0[2][2], nxt1[2][2];
    #pragma unroll
    for (int qq = 0; qq < 2; ++qq)
        #pragma unroll
        for (int kc = 0; kc < 2; ++kc) {
            cur0[qq][kc] = *(const float4*)(xRow[qq] + kc * 32);
            cur1[qq][kc] = *(const float4*)(xRow[qq] + kc * 32 + 4);
        }

    for (int ts = 0; ts < NTs; ++ts) {
        size_t kb = (size_t)ts * 128;
        #pragma unroll
        for (int kc = 0; kc < 2; ++kc) {
            GLOAD16(Bhb + gB + kb + kc * 64, smem + 32768 + kc * 4096 + lB);
            GLOAD16(Blb + gB + kb + kc * 64, smem + 40960 + kc * 4096 + lB);
        }
        if (ts + 1 < NTs) {
            #pragma unroll
            for (int qq = 0; qq < 2; ++qq)
                #pragma unroll
                for (int kc = 0; kc < 2; ++kc) {
                    nxt0[qq][kc] = *(const float4*)(xRow[qq] + (ts + 1) * 64 + kc * 32);
                    nxt1[qq][kc] = *(const float4*)(xRow[qq] + (ts + 1) * 64 + kc * 32 + 4);
                }
        }
        #pragma unroll
        for (int qq = 0; qq < 2; ++qq)
            #pragma unroll
            for (int kc = 0; kc < 2; ++kc) {
                float vv[8] = {cur0[qq][kc].x, cur0[qq][kc].y, cur0[qq][kc].z, cur0[qq][kc].w,
                               cur1[qq][kc].x, cur1[qq][kc].y, cur1[qq][kc].z, cur1[qq][kc].w};
                unsigned hp[4], lp[4];
                #pragma unroll
                for (int j = 0; j < 4; ++j) {
                    unsigned h = cvt_pk_bf16(vv[2 * j], vv[2 * j + 1]);
                    float h0 = __uint_as_float(h << 16);
                    float h1 = __uint_as_float(h & 0xFFFF0000u);
                    hp[j] = h;
                    lp[j] = cvt_pk_bf16(vv[2 * j] - h0, vv[2 * j + 1] - h1);
                }
                *(uint4*)(smem + kc * 8192 + aoff[qq])         = make_uint4(hp[0], hp[1], hp[2], hp[3]);
                *(uint4*)(smem + 16384 + kc * 8192 + aoff[qq]) = make_uint4(lp[0], lp[1], lp[2], lp[3]);
            }
        __syncthreads();
        #pragma unroll
        for (int kc = 0; kc < 2; ++kc) {
            short8 afh[MF], afl[MF], bfh[NF], bfl[NF];
            #pragma unroll
            for (int i = 0; i < MF; ++i) {
                int row = wm * SM + i * 16 + (lane & 15);
                int off = row * 64 + ((c16 ^ ((row >> 1) & 3)) * 16);
                afh[i] = *(const short8*)(smem + kc * 8192 + off);
                afl[i] = *(const short8*)(smem + 16384 + kc * 8192 + off);
            }
            #pragma unroll
            for (int j = 0; j < NF; ++j) {
                int row = wn * SN + j * 16 + (lane & 15);
                int off = row * 64 + ((c16 ^ ((row >> 1) & 3)) * 16);
                bfh[j] = *(const short8*)(smem + 32768 + kc * 4096 + off);
                bfl[j] = *(const short8*)(smem + 40960 + kc * 4096 + off);
            }
            #pragma unroll
            for (int i = 0; i < MF; ++i)
                #pragma unroll
                for (int j = 0; j < NF; ++j) {
                    acc[i][j] = __builtin_amdgcn_mfma_f32_16x16x32_bf16(afh[i], bfh[j], acc[i][j], 0, 0, 0);
                    acc[i][j] = __builtin_amdgcn_mfma_f32_16x16x32_bf16(afh[i], bfl[j], acc[i][j], 0, 0, 0);
                    acc[i][j] = __builtin_amdgcn_mfma_f32_16x16x32_bf16(afl[i], bfh[j], acc[i][j], 0, 0, 0);
                }
        }
        __syncthreads();
        #pragma unroll
        for (int qq = 0; qq < 2; ++qq)
            #pragma unroll
            for (int kc = 0; kc < 2; ++kc) { cur0[qq][kc] = nxt0[qq][kc]; cur1[qq][kc] = nxt1[qq][kc]; }
    }
    #pragma unroll
    for (int i = 0; i < MF; ++i) {
        int rbase = bm + wm * SM + i * 16 + (lane >> 4) * 4;
        #pragma unroll
        for (int j = 0; j < NF; ++j) {
            int col = bn + wn * SN + j * 16 + (lane & 15);
            #pragma unroll
            for (int rr = 0; rr < 4; ++rr)
                if (rbase + rr < M) Cp[(size_t)(rbase + rr) * NT + col] = acc[i][j][rr];
        }
    }
}

// ---------------- reduce partials + fused attention logits (layer 1) ----------------
// B0 += Cp1, then als/ald = per-head dots. One wave per row, 4 rows/block.
__launch_bounds__(256)
__global__ void reduce_al(float* __restrict__ B0, const float* __restrict__ Cp1,
                          const float* __restrict__ as_w, const float* __restrict__ ad_w,
                          float* __restrict__ als, float* __restrict__ ald) {
    int lane = threadIdx.x & 63, w = threadIdx.x >> 6;
    int row = blockIdx.x * 4 + w;
    if (row >= N_NODES) return;
    size_t base = (size_t)row * HC + lane * 4;
    float4 p0 = *(const float4*)&B0[base];
    float4 p1 = *(const float4*)&Cp1[base];
    float4 s = make_float4(p0.x + p1.x, p0.y + p1.y, p0.z + p1.z, p0.w + p1.w);
    *(float4*)&B0[base] = s;
    int head = lane >> 4;
    int cw = (lane & 15) * 4;                 // channel within head
    float ps = s.x * as_w[head * 64 + cw + 0] + s.y * as_w[head * 64 + cw + 1]
             + s.z * as_w[head * 64 + cw + 2] + s.w * as_w[head * 64 + cw + 3];
    float pd = s.x * ad_w[head * 64 + cw + 0] + s.y * ad_w[head * 64 + cw + 1]
             + s.z * ad_w[head * 64 + cw + 2] + s.w * ad_w[head * 64 + cw + 3];
    #pragma unroll
    for (int o = 1; o < 16; o <<= 1) {
        ps += __shfl_xor(ps, o, 64);
        pd += __shfl_xor(pd, o, 64);
    }
    if ((lane & 15) == 0) {
        als[row * 4 + head] = ps;
        ald[row * 4 + head] = pd;
    }
}

// ---------------- split-bf16 MFMA GEMM (bf16 A), BK=64, fused al ----------------
template<int BMT, int GY, int H>
__launch_bounds__(256)
__global__ void gemm_mfma(const ushort_t* __restrict__ Ah, const ushort_t* __restrict__ Al,
                          const ushort_t* __restrict__ BTh, const ushort_t* __restrict__ BTl,
                          float* __restrict__ C, const float* __restrict__ as_w,
                          const float* __restrict__ ad_w, float* __restrict__ als,
                          float* __restrict__ ald, int M, int K, int NT) {
    constexpr int BM = BMT, BN = 64, SM = BM / 2, SN = 32, MF = SM / 16, NF = 2;
    constexpr int AQ = BM / 64;
    constexpr int ASZ = BM * 64;
    __shared__ __align__(16) char smem[4 * ASZ + 16384];

    const int t = threadIdx.x, lane = t & 63, w = t >> 6;
    const int wm = w >> 1, wn = w & 1;
    const int nwg = gridDim.x;
    const int id = blockIdx.x;
    const int q = nwg >> 3, r = nwg & 7;
    const int xcd = id & 7, idx = id >> 3;
    const int logical = (xcd < r ? xcd * (q + 1) : r * (q + 1) + (xcd - r) * q) + idx;
    const int bm = (logical / GY) * BM, bn = (logical % GY) * BN;
    const int gchunk = ((lane & 3) ^ ((lane >> 3) & 3)) * 16;

    size_t gA[AQ]; int lA[AQ];
    #pragma unroll
    for (int qq = 0; qq < AQ; ++qq) {
        int inst = w * AQ + qq;
        int arow = inst * 16 + (lane >> 2);
        int grow = min(bm + arow, M - 1);
        gA[qq] = (size_t)grow * K * 2 + gchunk;
        lA[qq] = inst * 1024;
    }
    const int brow = w * 16 + (lane >> 2);
    const size_t gB = (size_t)(bn + brow) * K * 2 + gchunk;
    const int lB = w * 1024;

    const char* Ahb = (const char*)Ah;
    const char* Alb = (const char*)Al;
    const char* Bhb = (const char*)BTh;
    const char* Blb = (const char*)BTl;
    const int c16 = (lane >> 4);
    const int NTs = K / 64;

    f32x4 acc[MF][NF];
    #pragma unroll
    for (int i = 0; i < MF; ++i)
        #pragma unroll
        for (int j = 0; j < NF; ++j) acc[i][j] = (f32x4){0.f, 0.f, 0.f, 0.f};

    for (int ts = 0; ts < NTs; ++ts) {
        size_t kb = (size_t)ts * 128;
        #pragma unroll
        for (int kc = 0; kc < 2; ++kc) {
            #pragma unroll
            for (int qq = 0; qq < AQ; ++qq) {
                GLOAD16(Ahb + gA[qq] + kb + kc * 64, smem + kc * ASZ + lA[qq]);
                GLOAD16(Alb + gA[qq] + kb + kc * 64, smem + 2 * ASZ + kc * ASZ + lA[qq]);
            }
            GLOAD16(Bhb + gB + kb + kc * 64, smem + 4 * ASZ + kc * 4096 + lB);
            GLOAD16(Blb + gB + kb + kc * 64, smem + 4 * ASZ + 8192 + kc * 4096 + lB);
        }
        __syncthreads();
        #pragma unroll
        for (int kc = 0; kc < 2; ++kc) {
            short8 afh[MF], afl[MF], bfh[NF], bfl[NF];
            #pragma unroll
            for (int i = 0; i < MF; ++i) {
                int row = wm * SM + i * 16 + (lane & 15);
                int off = row * 64 + ((c16 ^ ((row >> 1) & 3)) * 16);
                afh[i] = *(const short8*)(smem + kc * ASZ + off);
                afl[i] = *(const short8*)(smem + 2 * ASZ + kc * ASZ + off);
            }
            #pragma unroll
            for (int j = 0; j < NF; ++j) {
                int row = wn * SN + j * 16 + (lane & 15);
                int off = row * 64 + ((c16 ^ ((row >> 1) & 3)) * 16);
                bfh[j] = *(const short8*)(smem + 4 * ASZ + kc * 4096 + off);
                bfl[j] = *(const short8*)(smem + 4 * ASZ + 8192 + kc * 4096 + off);
            }
            #pragma unroll
            for (int i = 0; i < MF; ++i)
                #pragma unroll
                for (int j = 0; j < NF; ++j) {
                    acc[i][j] = __builtin_amdgcn_mfma_f32_16x16x32_bf16(afh[i], bfh[j], acc[i][j], 0, 0, 0);
                    acc[i][j] = __builtin_amdgcn_mfma_f32_16x16x32_bf16(afh[i], bfl[j], acc[i][j], 0, 0, 0);
                    acc[i][j] = __builtin_amdgcn_mfma_f32_16x16x32_bf16(afl[i], bfh[j], acc[i][j], 0, 0, 0);
                }
        }
        __syncthreads();
    }
    #pragma unroll
    for (int i = 0; i < MF; ++i) {
        int rbase = bm + wm * SM + i * 16 + (lane >> 4) * 4;
        #pragma unroll
        for (int j = 0; j < NF; ++j) {
            int col = bn + wn * SN + j * 16 + (lane & 15);
            #pragma unroll
            for (int rr = 0; rr < 4; ++rr)
                if (rbase + rr < M) C[(size_t)(rbase + rr) * NT + col] = acc[i][j][rr];
        }
    }
    AL_EPILOGUE()
}

// ---------------- alpha precompute: segment softmax -> alpha[H][ET] ----------------
template<int H>
__launch_bounds__(256)
__global__ void alpha_kernel(const float* __restrict__ als, const float* __restrict__ ald,
                             const int* __restrict__ row_ptr, const int* __restrict__ col,
                             float* __restrict__ alpha) {
    int lane = threadIdx.x & 63, w = threadIdx.x >> 6;
    int dst = blockIdx.x * 4 + w;
    if (dst >= N_NODES) return;
    int beg = row_ptr[dst], deg = row_ptr[dst + 1] - beg;
    constexpr int ES = 64 / H;
    int i_loc = lane / H, hh = lane % H;
    float ad = ald[dst * H + hh];
    float m = -1e30f, den = 0.f;
    for (int base = 0; base < deg; base += ES) {
        int i = base + i_loc;
        if (i < deg) {
            float e = als[col[beg + i] * H + hh] + ad;
            e = (e > 0.f) ? e : 0.2f * e;
            float nm = fmaxf(m, e);
            den = den * __expf(m - nm) + __expf(e - nm);
            m = nm;
        }
    }
    #pragma unroll
    for (int off = H; off < 64; off <<= 1) {
        float mo = __shfl_xor(m, off, 64);
        float dn = __shfl_xor(den, off, 64);
        float nm = fmaxf(m, mo);
        den = den * __expf(m - nm) + dn * __expf(mo - nm);
        m = nm;
    }
    float rden = 1.f / (den + 1e-16f);
    for (int base = 0; base < deg; base += ES) {
        int i = base + i_loc;
        if (i < deg) {
            float e = als[col[beg + i] * H + hh] + ad;
            e = (e > 0.f) ? e : 0.2f * e;
            alpha[(size_t)hh * ET + beg + i] = __expf(e - m) * rden;
        }
    }
}

// ---------------- channel-sliced aggregation v4: 2-deep unroll, optional classifier ----------------
template<int CT, int CW, int H, bool RELU, bool SPLIT, bool CLS>
__launch_bounds__(256)
__global__ void agg_v4(const float* __restrict__ h, const float* __restrict__ alpha,
                       const int* __restrict__ row_ptr, const int* __restrict__ col,
                       const float* __restrict__ bias,
                       ushort_t* __restrict__ oh, ushort_t* __restrict__ ol,
                       float* __restrict__ of,
                       const float* __restrict__ wc, const float* __restrict__ bc,
                       float* __restrict__ cls_out) {
    constexpr int NS  = CT / CW;         // slices (== H)
    constexpr int LPT = CW / 4;          // lanes per team (16)
    constexpr int TPW = 64 / LPT;        // teams per wave (4)
    static_assert(NS == H, "slice==head mapping");
    __shared__ int   s_src[4][64];
    __shared__ float s_alp[4][64];
    const int nwg = gridDim.x;
    const int q = nwg >> 3;
    int id = blockIdx.x;
    int logical = (id & 7) * q + (id >> 3);
    int slice = logical / (N_NODES / 4);
    int g = logical - slice * (N_NODES / 4);
    int lane = threadIdx.x & 63, w = threadIdx.x >> 6;
    int dst = g * 4 + w;
    int beg = row_ptr[dst], deg = row_ptr[dst + 1] - beg;
    int team = lane / LPT;
    int cc = (lane & (LPT - 1)) * 4;

    const int*   colP = col + beg;
    const float* aP   = alpha + (size_t)slice * ET + beg;
    const float* hS   = h + slice * CW + cc;

    float4 acc  = make_float4(0.f, 0.f, 0.f, 0.f);
    float4 acc2 = make_float4(0.f, 0.f, 0.f, 0.f);
    for (int base = 0; base < deg; base += 64) {
        int cnt = min(64, deg - base);
        if (lane < cnt) {
            s_src[w][lane] = colP[base + lane];
            s_alp[w][lane] = aP[base + lane];
        }
        int i = team;
        for (; i + TPW < cnt; i += 2 * TPW) {
            int   s0 = s_src[w][i],       s1 = s_src[w][i + TPW];
            float a0 = s_alp[w][i],       a1 = s_alp[w][i + TPW];
            float4 h0 = *(const float4*)&hS[s0 * CT];
            float4 h1 = *(const float4*)&hS[s1 * CT];
            acc.x  += a0 * h0.x; acc.y  += a0 * h0.y; acc.z  += a0 * h0.z; acc.w  += a0 * h0.w;
            acc2.x += a1 * h1.x; acc2.y += a1 * h1.y; acc2.z += a1 * h1.z; acc2.w += a1 * h1.w;
        }
        if (i < cnt) {
            int   s0 = s_src[w][i];
            float a0 = s_alp[w][i];
            float4 h0 = *(const float4*)&hS[s0 * CT];
            acc.x += a0 * h0.x; acc.y += a0 * h0.y; acc.z += a0 * h0.z; acc.w += a0 * h0.w;
        }
    }
    acc.x += acc2.x; acc.y += acc2.y; acc.z += acc2.z; acc.w += acc2.w;
    #pragma unroll
    for (int off = LPT; off < 64; off <<= 1) {
        acc.x += __shfl_xor(acc.x, off, 64);
        acc.y += __shfl_xor(acc.y, off, 64);
        acc.z += __shfl_xor(acc.z, off, 64);
        acc.w += __shfl_xor(acc.w, off, 64);
    }
    if (team == 0) {
        int ch = slice * CW + cc;
        float4 bv = *(const float4*)&bias[ch];
        float v0 = acc.x + bv.x, v1 = acc.y + bv.y, v2 = acc.z + bv.z, v3 = acc.w + bv.w;
        if (RELU) {
            v0 = fmaxf(v0, 0.f); v1 = fmaxf(v1, 0.f);
            v2 = fmaxf(v2, 0.f); v3 = fmaxf(v3, 0.f);
        }
        if (CLS) {
            // classifier fused: out[dst][k] = sum_c v[c]*wc[c][k] + bc[k]
            float ps[NC];
            #pragma unroll
            for (int k = 0; k < NC; ++k)
                ps[k] = v0 * wc[(cc + 0) * NC + k] + v1 * wc[(cc + 1) * NC + k]
                      + v2 * wc[(cc + 2) * NC + k] + v3 * wc[(cc + 3) * NC + k];
            #pragma unroll
            for (int o = 1; o < 16; o <<= 1)
                #pragma unroll
                for (int k = 0; k < NC; ++k) ps[k] += __shfl_xor(ps[k], o, 64);
            if (lane == 0) {
                #pragma unroll
                for (int k = 0; k < NC; ++k) cls_out[(size_t)dst * NC + k] = ps[k] + bc[k];
            }
        } else {
            size_t idx = (size_t)dst * CT + ch;
            if (SPLIT) {
                ushort4 h4, l4;
                h4.x = f2bf(v0); l4.x = f2bf(v0 - bf2f(h4.x));
                h4.y = f2bf(v1); l4.y = f2bf(v1 - bf2f(h4.y));
                h4.z = f2bf(v2); l4.z = f2bf(v2 - bf2f(h4.z));
                h4.w = f2bf(v3); l4.w = f2bf(v3 - bf2f(h4.w));
                *(ushort4*)&oh[idx] = h4;
                *(ushort4*)&ol[idx] = l4;
            } else {
                *(float4*)&of[idx] = make_float4(v0, v1, v2, v3);
            }
        }
    }
}

extern "C" void kernel_launch(void* const* d_in, const int* in_sizes, int n_in,
                              void* d_out, int out_size, void* d_ws, size_t ws_size,
                              hipStream_t stream) {
    const float* x   = (const float*)d_in[0];
    const int*   ei  = (const int*)d_in[1];
    const float* w1  = (const float*)d_in[2];
    const float* as1 = (const float*)d_in[3];
    const float* ad1 = (const float*)d_in[4];
    const float* b1  = (const float*)d_in[5];
    const float* w2  = (const float*)d_in[6];
    const float* as2 = (const float*)d_in[7];
    const float* ad2 = (const float*)d_in[8];
    const float* b2  = (const float*)d_in[9];
    const float* w3  = (const float*)d_in[10];
    const float* as3 = (const float*)d_in[11];
    const float* ad3 = (const float*)d_in[12];
    const float* b3  = (const float*)d_in[13];
    const float* wc  = (const float*)d_in[14];
    const float* bc  = (const float*)d_in[15];
    float* out = (float*)d_out;

    char* ws = (char*)d_ws;
    size_t off = 0;
    auto alloc = [&](size_t bytes) -> char* {
        char* p = ws + off;
        off = (off + bytes + 255) & ~(size_t)255;
        return p;
    };

    int* counts  = (int*)alloc(N_NODES * 4);
    int* cursor  = (int*)alloc(N_NODES * 4);
    int* row_ptr = (int*)alloc((N_NODES + 1) * 4);
    int* colidx  = (int*)alloc(ET * 4);
    float* als   = (float*)alloc(N_NODES * 4 * 4);
    float* ald   = (float*)alloc(N_NODES * 4 * 4);
    float* alpha = (float*)alloc((size_t)4 * ET * 4);        // [H][ET]
    float* B0    = (float*)alloc((size_t)N_NODES * HC * 4);
    float* Cp1   = (float*)alloc((size_t)N_NODES * HC * 4);  // split-K partial

    ushort_t* w1Th = (ushort_t*)alloc((size_t)F_IN * HC * 2);
    ushort_t* w1Tl = (ushort_t*)alloc((size_t)F_IN * HC * 2);
    ushort_t* w2Th = (ushort_t*)alloc((size_t)HC * HC * 2);
    ushort_t* w2Tl = (ushort_t*)alloc((size_t)HC * HC * 2);
    ushort_t* w3Th = (ushort_t*)alloc((size_t)HC * 64 * 2);
    ushort_t* w3Tl = (ushort_t*)alloc((size_t)HC * 64 * 2);
    ushort_t* B1h  = (ushort_t*)alloc((size_t)N_NODES * HC * 2);
    ushort_t* B1l  = (ushort_t*)alloc((size_t)N_NODES * HC * 2);

    // ---- CSR build ----
    hipMemsetAsync(counts, 0, N_NODES * sizeof(int), stream);
    int eb = (ET + 255) / 256;
    count_kernel<<<eb, 256, 0, stream>>>(ei, counts);
    scan_kernel<<<1, 1024, 0, stream>>>(counts, row_ptr, cursor);
    scatter_kernel<<<eb, 256, 0, stream>>>(ei, cursor, colidx);

    // ---- weight precision split ----
    split_T<<<(F_IN * HC + 255) / 256, 256, 0, stream>>>(w1, w1Th, w1Tl, F_IN, HC);
    split_T<<<(HC * HC + 255) / 256, 256, 0, stream>>>(w2, w2Th, w2Tl, HC, HC);
    split_T<<<(HC * 64 + 255) / 256, 256, 0, stream>>>(w3, w3Th, w3Tl, HC, 64);

    const int nwg128 = ((N_NODES + 127) / 128) * (HC / 64);  // 628
    const int nblk_dst = N_NODES / 4;                        // 5000
    // ---- layer 1: split-K GEMM + reduce/al ----
    gemm_f32a_ks<4><<<2 * nwg128, 256, 0, stream>>>(x, w1Th, w1Tl, B0, Cp1, N_NODES, F_IN, HC);
    reduce_al<<<nblk_dst, 256, 0, stream>>>(B0, Cp1, as1, ad1, als, ald);
    alpha_kernel<4><<<nblk_dst, 256, 0, stream>>>(als, ald, row_ptr, colidx, alpha);
    agg_v4<256, 64, 4, true, true, false><<<4 * nblk_dst, 256, 0, stream>>>(
        B0, alpha, row_ptr, colidx, b1, B1h, B1l, nullptr, nullptr, nullptr, nullptr);
    // ---- layer 2 ----
    gemm_mfma<128, 4, 4><<<nwg128, 256, 0, stream>>>(B1h, B1l, w2Th, w2Tl, B0, as2, ad2,
                                                     als, ald, N_NODES, HC, HC);
    alpha_kernel<4><<<nblk_dst, 256, 0, stream>>>(als, ald, row_ptr, colidx, alpha);
    agg_v4<256, 64, 4, true, true, false><<<4 * nblk_dst, 256, 0, stream>>>(
        B0, alpha, row_ptr, colidx, b2, B1h, B1l, nullptr, nullptr, nullptr, nullptr);
    // ---- layer 3 (H=1, C=64) + fused classifier ----
    const int nwg3 = (N_NODES + 63) / 64;                    // 313
    gemm_mfma<64, 1, 1><<<nwg3, 256, 0, stream>>>(B1h, B1l, w3Th, w3Tl, B0, as3, ad3,
                                                  als, ald, N_NODES, HC, 64);
    alpha_kernel<1><<<nblk_dst, 256, 0, stream>>>(als, ald, row_ptr, colidx, alpha);
    agg_v4<64, 64, 1, false, false, true><<<nblk_dst, 256, 0, stream>>>(
        B0, alpha, row_ptr, colidx, b3, nullptr, nullptr, nullptr, wc, bc, out);
}